// Round 8
// baseline (512.408 us; speedup 1.0000x reference)
//
#include <hip/hip_runtime.h>

#define NN 50000
#define NE 800000
#define NG 64
#define FD 64
#define BN_EPS 1e-5f
#define SCAN_B 256
#define NBIN 98            // ceil(50000/512)
#define BINCAP 12288
#define SCH 4096
#define SCH_NBLK ((NE + SCH - 1) / SCH)          // 196
#define INV_NN (1.0f / NN)
#define NSLOT 256          // bnpart contention-spread slots
#define MM_NBLK ((NN + 3) / 4)                   // 12500

// ---------------- CSR build: binned two-pass ----------------
__global__ __launch_bounds__(256) void k_binscatter(const int* __restrict__ row,
                                                    const int* __restrict__ col,
                                                    int* __restrict__ gcnt,
                                                    int* __restrict__ bins) {
    __shared__ int stage[SCH];
    __shared__ int cnt[NBIN], off[NBIN + 1], cur[NBIN], gbase[NBIN];
    int t = threadIdx.x;
    int e0 = blockIdx.x * SCH;
    int nk = NE - e0; if (nk > SCH) nk = SCH;
    if (nk <= 0) return;
    for (int b = t; b < NBIN; b += 256) cnt[b] = 0;
    __syncthreads();
    for (int k = t; k < nk; k += 256) {
        int c = col[e0 + k];
        atomicAdd(&cnt[c >> 9], 1);
    }
    __syncthreads();
    if (t == 0) {
        int run = 0;
        for (int b = 0; b < NBIN; ++b) { off[b] = run; run += cnt[b]; }
        off[NBIN] = run;
    }
    __syncthreads();
    if (t < NBIN) {
        cur[t] = off[t];
        gbase[t] = t * BINCAP + atomicAdd(&gcnt[t], cnt[t]);
    }
    __syncthreads();
    for (int k = t; k < nk; k += 256) {
        int c = col[e0 + k];
        int r = row[e0 + k];
        int b = c >> 9;
        int pos = atomicAdd(&cur[b], 1);
        stage[pos] = ((c & 511) << 16) | r;
    }
    __syncthreads();
    for (int k = t; k < nk; k += 256) {
        int lo = 0, hi = NBIN - 1;
        while (lo < hi) {
            int mid = (lo + hi + 1) >> 1;
            if (off[mid] <= k) lo = mid; else hi = mid - 1;
        }
        bins[gbase[lo] + (k - off[lo])] = stage[k];
    }
}

// per-bin degree hist + in-block scan + dinv + xd
__global__ __launch_bounds__(256) void k_binscan(const int* __restrict__ gcnt,
                                                 const int* __restrict__ bins,
                                                 const float* __restrict__ x,
                                                 int* __restrict__ cursor,
                                                 int* __restrict__ bsum,
                                                 float* __restrict__ dinv,
                                                 float* __restrict__ xd) {
    __shared__ int ldeg[512];
    __shared__ int psc[256];
    int b = blockIdx.x, t = threadIdx.x;
    for (int l = t; l < 512; l += 256) ldeg[l] = 0;
    __syncthreads();
    int nb = gcnt[b];
    const int* bp = bins + b * BINCAP;
    for (int k = t; k < nb; k += 256) atomicAdd(&ldeg[bp[k] >> 16], 1);
    __syncthreads();
    int d0 = ldeg[2 * t], d1 = ldeg[2 * t + 1];
    int pv = d0 + d1;
    psc[t] = pv;
    __syncthreads();
    for (int off = 1; off < 256; off <<= 1) {
        int u = (t >= off) ? psc[t - off] : 0;
        __syncthreads();
        psc[t] += u;
        __syncthreads();
    }
    int excl = psc[t] - pv;
    int base = b << 9;
    int i0 = base + 2 * t, i1 = i0 + 1;
    if (i0 < NN) {
        cursor[i0] = excl;
        float dv = rsqrtf((float)d0 + 1.0f);
        dinv[i0] = dv; xd[i0] = x[i0] * dv;
    }
    if (i1 < NN) {
        cursor[i1] = excl + d0;
        float dv = rsqrtf((float)d1 + 1.0f);
        dinv[i1] = dv; xd[i1] = x[i1] * dv;
    }
    if (t == 255) bsum[b] = psc[255];
}

// scan the 98 bin sums -> exclusive bin offsets; zero stats
__global__ __launch_bounds__(SCAN_B) void k_scan_top(int* __restrict__ bsum,
                                                     float* __restrict__ stats) {
    __shared__ int sh[SCAN_B];
    int t = threadIdx.x;
    if (t < 2) stats[t] = 0.0f;
    int v = (t < NBIN) ? bsum[t] : 0;
    sh[t] = v;
    __syncthreads();
    for (int off = 1; off < SCAN_B; off <<= 1) {
        int u = (t >= off) ? sh[t - off] : 0;
        __syncthreads();
        sh[t] += u;
        __syncthreads();
    }
    if (t < NBIN) bsum[t] = sh[t] - v;
}

// per-bin fill of eidx + fused layer-1 scalar propagation + stats
__global__ __launch_bounds__(256) void k_binfill_l1(const int* __restrict__ gcnt,
                                                    const int* __restrict__ bins,
                                                    const int* __restrict__ cursor,
                                                    const int* __restrict__ bsum,
                                                    int* __restrict__ eidx,
                                                    const float* __restrict__ xd,
                                                    const float* __restrict__ x,
                                                    const float* __restrict__ dinv,
                                                    float* __restrict__ s,
                                                    float* __restrict__ stats) {
    __shared__ int lstart[512], lcur[512];
    __shared__ float ls[256], lq[256];
    int b = blockIdx.x, t = threadIdx.x;
    int base = b << 9;
    int bofs = bsum[b];
    for (int l = t; l < 512; l += 256) {
        int i = base + l;
        int st = (i < NN) ? cursor[i] + bofs : 0;
        lstart[l] = st; lcur[l] = st;
    }
    __syncthreads();
    int nb = gcnt[b];
    const int* bp = bins + b * BINCAP;
    for (int k = t; k < nb; k += 256) {
        int v = bp[k];
        int pos = atomicAdd(&lcur[v >> 16], 1);
        eidx[pos] = v & 0xFFFF;
    }
    __syncthreads();
    float a = 0.0f, q = 0.0f;
    #pragma unroll
    for (int half = 0; half < 2; ++half) {
        int l = t + half * 256;
        int i = base + l;
        if (i < NN) {
            float acc = 0.0f;
            int e0 = lstart[l], e1 = lcur[l];
            for (int k = e0; k < e1; ++k) acc += xd[eidx[k]];
            float di = dinv[i];
            float sv = di * (acc + di * x[i]);
            s[i] = sv;
            a += sv; q += sv * sv;
        }
    }
    ls[t] = a; lq[t] = q;
    __syncthreads();
    for (int st = 128; st > 0; st >>= 1) {
        if (t < st) { ls[t] += ls[t + st]; lq[t] += lq[t + st]; }
        __syncthreads();
    }
    if (t == 0) { atomicAdd(&stats[0], ls[0]); atomicAdd(&stats[1], lq[0]); }
}

// ---------------- fused coeffs + activation + 64x64 matmul (+ bnpart zero) ----------------
__global__ __launch_bounds__(256) void k_mm_l1(const float* __restrict__ s,
                                               const float* __restrict__ stats,
                                               const float* __restrict__ W1,
                                               const float* __restrict__ g1,
                                               const float* __restrict__ bt1,
                                               const float* __restrict__ W,
                                               float* __restrict__ h,
                                               float* __restrict__ bnpart) {
    __shared__ float Ws[64 * 64];
    __shared__ float xs[4 * 64];
    __shared__ float als[64], cls[64];
    int t = threadIdx.x;
    {   // zero bnpart slice (128*NSLOT floats over MM_NBLK blocks)
        int idx = blockIdx.x * 3 + (t & 3);
        if (t < 3 + 1 && (t & 3) < 3 && idx < 128 * NSLOT && t < 3) bnpart[idx] = 0.0f;
    }
    for (int k = t; k < 64 * 64; k += 256) Ws[k] = W[k];
    if (t < 64) {
        float mean = stats[0] * INV_NN;
        float var  = stats[1] * INV_NN - mean * mean;
        float w = W1[t];
        float rinv = rsqrtf(var * w * w + BN_EPS);
        float aa = g1[t] * w * rinv;
        als[t] = aa;
        cls[t] = bt1[t] - aa * mean;
    }
    __syncthreads();
    int n0 = blockIdx.x * 4;
    int j = t & 63, n = t >> 6;
    int node = n0 + n;
    float sv = (node < NN) ? s[node] : 0.0f;
    xs[t] = fmaxf(als[j] * sv + cls[j], 0.0f);
    __syncthreads();
    if (node < NN) {
        float acc = 0.f;
        #pragma unroll
        for (int k = 0; k < 64; ++k) acc += xs[n * 64 + k] * Ws[k * 64 + j];
        h[node * 64 + j] = acc;
    }
}

__global__ __launch_bounds__(256) void k_mm_bn(const float* __restrict__ src,
                                               const float* __restrict__ bnsum,
                                               const float* __restrict__ bnsq,
                                               const float* __restrict__ g,
                                               const float* __restrict__ bt,
                                               const float* __restrict__ W,
                                               float* __restrict__ h,
                                               float* __restrict__ bnpart) {
    __shared__ float Ws[64 * 64];
    __shared__ float xs[4 * 64];
    __shared__ float scl[64], shf[64];
    int t = threadIdx.x;
    {
        int idx = blockIdx.x * 3 + t;
        if (t < 3 && idx < 128 * NSLOT) bnpart[idx] = 0.0f;
    }
    for (int k = t; k < 64 * 64; k += 256) Ws[k] = W[k];
    if (t < 64) {
        float mean = bnsum[t] * INV_NN;
        float var  = bnsq[t] * INV_NN - mean * mean;
        float rinv = rsqrtf(var + BN_EPS);
        float sc = g[t] * rinv;
        scl[t] = sc;
        shf[t] = bt[t] - sc * mean;
    }
    __syncthreads();
    int n0 = blockIdx.x * 4;
    int j = t & 63, n = t >> 6;
    int node = n0 + n;
    int gidx = n0 * 64 + t;
    float v = (gidx < NN * 64) ? src[gidx] : 0.0f;
    xs[t] = fmaxf(scl[j] * v + shf[j], 0.0f);
    __syncthreads();
    if (node < NN) {
        float acc = 0.f;
        #pragma unroll
        for (int k = 0; k < 64; ++k) acc += xs[n * 64 + k] * Ws[k * 64 + j];
        h[node * 64 + j] = acc;
    }
}

// ---------------- CSR gather aggregation + fused BN partial stats ----------------
// NN % 4 == 0 and grid == MM_NBLK, so every node is valid.
__global__ __launch_bounds__(256) void k_gather(const int* __restrict__ cursor,
                                                const int* __restrict__ bsum,
                                                const int* __restrict__ eidx,
                                                const float* __restrict__ dinv,
                                                const float* __restrict__ h,
                                                const float* __restrict__ b,
                                                float* __restrict__ agg,
                                                float* __restrict__ bnpart) {
    __shared__ float tile[4][64];
    int n = threadIdx.x >> 6;
    int node = blockIdx.x * 4 + n;
    int lane = threadIdx.x & 63;
    int eslot = lane >> 4;
    int fb = (lane & 15) << 2;
    int start = cursor[node] + bsum[node >> 9];
    int end = (node < NN - 1) ? cursor[node + 1] + bsum[(node + 1) >> 9] : NE;
    float4 acc0 = make_float4(0.f, 0.f, 0.f, 0.f);
    float4 acc1 = make_float4(0.f, 0.f, 0.f, 0.f);
    int e = start + eslot;
    for (; e + 4 < end; e += 8) {
        int r0 = eidx[e], r1 = eidx[e + 4];
        float dr0 = dinv[r0], dr1 = dinv[r1];
        const float4 h0 = *reinterpret_cast<const float4*>(&h[r0 * 64 + fb]);
        const float4 h1 = *reinterpret_cast<const float4*>(&h[r1 * 64 + fb]);
        acc0.x += h0.x * dr0; acc0.y += h0.y * dr0; acc0.z += h0.z * dr0; acc0.w += h0.w * dr0;
        acc1.x += h1.x * dr1; acc1.y += h1.y * dr1; acc1.z += h1.z * dr1; acc1.w += h1.w * dr1;
    }
    if (e < end) {
        int r = eidx[e];
        float dr = dinv[r];
        const float4 hv = *reinterpret_cast<const float4*>(&h[r * 64 + fb]);
        acc0.x += hv.x * dr; acc0.y += hv.y * dr; acc0.z += hv.z * dr; acc0.w += hv.w * dr;
    }
    acc0.x += acc1.x; acc0.y += acc1.y; acc0.z += acc1.z; acc0.w += acc1.w;
    acc0.x += __shfl_xor(acc0.x, 16); acc0.y += __shfl_xor(acc0.y, 16);
    acc0.z += __shfl_xor(acc0.z, 16); acc0.w += __shfl_xor(acc0.w, 16);
    acc0.x += __shfl_xor(acc0.x, 32); acc0.y += __shfl_xor(acc0.y, 32);
    acc0.z += __shfl_xor(acc0.z, 32); acc0.w += __shfl_xor(acc0.w, 32);
    if (lane < 16) {
        float dc = dinv[node];
        const float4 hv = *reinterpret_cast<const float4*>(&h[node * 64 + fb]);
        const float4 bv = *reinterpret_cast<const float4*>(&b[fb]);
        float4 o;
        o.x = dc * (acc0.x + dc * hv.x) + bv.x;
        o.y = dc * (acc0.y + dc * hv.y) + bv.y;
        o.z = dc * (acc0.z + dc * hv.z) + bv.z;
        o.w = dc * (acc0.w + dc * hv.w) + bv.w;
        *reinterpret_cast<float4*>(&agg[node * 64 + fb]) = o;
        tile[n][fb]     = o.x;
        tile[n][fb + 1] = o.y;
        tile[n][fb + 2] = o.z;
        tile[n][fb + 3] = o.w;
    }
    __syncthreads();
    int t = threadIdx.x;
    if (t < 64) {
        float v0 = tile[0][t], v1 = tile[1][t], v2 = tile[2][t], v3 = tile[3][t];
        float sm = v0 + v1 + v2 + v3;
        float sq = v0 * v0 + v1 * v1 + v2 * v2 + v3 * v3;
        int slot = blockIdx.x & (NSLOT - 1);
        atomicAdd(&bnpart[t * NSLOT + slot], sm);
        atomicAdd(&bnpart[(64 + t) * NSLOT + slot], sq);
    }
}

// reduce bnpart -> bnsum/bnsq; optionally zero pooled/cnt
__global__ __launch_bounds__(256) void k_bn_reduce(const float* __restrict__ bnpart,
                                                   float* __restrict__ bnsum,
                                                   float* __restrict__ bnsq,
                                                   float* __restrict__ pooledz,
                                                   float* __restrict__ cntz) {
    int t = threadIdx.x;
    if (t < 128) {
        float sm = 0.0f;
        const float* p = bnpart + t * NSLOT;
        for (int k = 0; k < NSLOT; ++k) sm += p[k];
        if (t < 64) bnsum[t] = sm; else bnsq[t - 64] = sm;
    }
    if (pooledz != nullptr) {
        for (int k = t; k < 64 * 64; k += 256) pooledz[k] = 0.0f;
        if (t < 64) cntz[t] = 0.0f;
    }
}

// ---------------- fused BN-finalize + BN + pooling (segmented) ----------------
__global__ __launch_bounds__(256) void k_pool_bn(const float* __restrict__ agg,
                                                 const float* __restrict__ bnsum,
                                                 const float* __restrict__ bnsq,
                                                 const float* __restrict__ g4,
                                                 const float* __restrict__ bt4,
                                                 const int* __restrict__ batch,
                                                 float* __restrict__ pooled,
                                                 float* __restrict__ cnt) {
    const int wpb = 4;
    int wave = blockIdx.x * wpb + (threadIdx.x >> 6);
    int lane = threadIdx.x & 63;
    const int nwaves = gridDim.x * wpb;
    int chunk = (NN + nwaves - 1) / nwaves;
    int i0 = wave * chunk;
    int i1 = i0 + chunk; if (i1 > NN) i1 = NN;
    if (i0 >= NN) return;
    float mean = bnsum[lane] * INV_NN;
    float var  = bnsq[lane] * INV_NN - mean * mean;
    float rinv = rsqrtf(var + BN_EPS);
    float sc = g4[lane] * rinv;
    float sh = bt4[lane] - sc * mean;
    float acc = 0.0f;
    int curb = batch[i0];
    int runlen = 0;
    for (int i = i0; i < i1; ++i) {
        int b = batch[i];
        if (b != curb) {
            atomicAdd(&pooled[curb * 64 + lane], acc);
            if (lane == 0) atomicAdd(&cnt[curb], (float)runlen);
            acc = 0.0f; runlen = 0; curb = b;
        }
        acc += fmaxf(sc * agg[i * 64 + lane] + sh, 0.0f);
        ++runlen;
    }
    atomicAdd(&pooled[curb * 64 + lane], acc);
    if (lane == 0) atomicAdd(&cnt[curb], (float)runlen);
}

__global__ __launch_bounds__(128) void k_fc(const float* __restrict__ pooled, const float* __restrict__ cnt,
                                            const float* __restrict__ fw1, const float* __restrict__ fb1,
                                            const float* __restrict__ fw2, const float* __restrict__ fb2,
                                            float* __restrict__ out) {
    __shared__ float p[64], hsh[128];
    int g = blockIdx.x, t = threadIdx.x;
    if (t < 64) {
        float c = cnt[g]; c = c < 1.f ? 1.f : c;
        p[t] = pooled[g * 64 + t] / c;
    }
    __syncthreads();
    float acc = fb1[t];
    #pragma unroll 8
    for (int k = 0; k < 64; ++k) acc += p[k] * fw1[t * 64 + k];
    hsh[t] = fmaxf(acc, 0.f);
    __syncthreads();
    if (t < 10) {
        float o = fb2[t];
        #pragma unroll 8
        for (int k = 0; k < 128; ++k) o += hsh[k] * fw2[t * 128 + k];
        out[g * 10 + t] = o;
    }
}

// ---------------- launch ----------------
extern "C" void kernel_launch(void* const* d_in, const int* in_sizes, int n_in,
                              void* d_out, int out_size, void* d_ws, size_t ws_size,
                              hipStream_t stream) {
    const float* x   = (const float*)d_in[0];
    const int* ei    = (const int*)d_in[1];
    const int* batch = (const int*)d_in[2];
    const float* W[5]  = {nullptr, (const float*)d_in[3],  (const float*)d_in[7],
                                   (const float*)d_in[11], (const float*)d_in[15]};
    const float* bb[5] = {nullptr, (const float*)d_in[4],  (const float*)d_in[8],
                                   (const float*)d_in[12], (const float*)d_in[16]};
    const float* gg[5] = {nullptr, (const float*)d_in[5],  (const float*)d_in[9],
                                   (const float*)d_in[13], (const float*)d_in[17]};
    const float* bt[5] = {nullptr, (const float*)d_in[6],  (const float*)d_in[10],
                                   (const float*)d_in[14], (const float*)d_in[18]};
    const float* fw1 = (const float*)d_in[19];
    const float* fb1 = (const float*)d_in[20];
    const float* fw2 = (const float*)d_in[21];
    const float* fb2 = (const float*)d_in[22];
    float* out = (float*)d_out;

    const int* row = ei;
    const int* col = ei + NE;

    float* ws = (float*)d_ws;
    int*   cursor  = (int*)ws;              // N
    int*   eidx    = (int*)(ws + 50000);    // E
    float* dinv    = ws + 850000;           // N
    float* xd      = ws + 900000;           // N
    int*   bsum    = (int*)(ws + 950000);   // NBIN
    float* s       = ws + 951000;           // N
    float* stats   = ws + 1001008;          // 2
    float* bnsum   = ws + 1001072;          // 64
    float* bnsq    = ws + 1001136;          // 64
    float* pooled  = ws + 1001360;          // 64*64
    float* cnt     = ws + 1005456;          // 64
    float* bnpart  = ws + 1006000;          // 128*NSLOT = 32768
    int*   gcnt    = (int*)(ws + 1056000);  // NBIN
    float* hbuf    = ws + 1100000;          // N*64 (bins alias pre-layer2)
    int*   bins    = (int*)(ws + 1100000);  // NBIN*BINCAP ints
    float* aggbuf  = ws + 4300000;          // N*64

    const int B = 256;

    // CSR build (binned) + dinv + xd
    hipMemsetAsync(gcnt, 0, NBIN * sizeof(int), stream);
    k_binscatter<<<SCH_NBLK, B, 0, stream>>>(row, col, gcnt, bins);
    k_binscan<<<NBIN, B, 0, stream>>>(gcnt, bins, x, cursor, bsum, dinv, xd);
    k_scan_top<<<1, SCAN_B, 0, stream>>>(bsum, stats);
    // fill eidx + layer-1 scalar propagation + stats
    k_binfill_l1<<<NBIN, B, 0, stream>>>(gcnt, bins, cursor, bsum, eidx, xd, x, dinv, s, stats);

    // layer 2
    k_mm_l1<<<MM_NBLK, B, 0, stream>>>(s, stats, W[1], gg[1], bt[1], W[2], hbuf, bnpart);
    k_gather<<<MM_NBLK, B, 0, stream>>>(cursor, bsum, eidx, dinv, hbuf, bb[2], aggbuf, bnpart);
    k_bn_reduce<<<1, B, 0, stream>>>(bnpart, bnsum, bnsq, nullptr, nullptr);

    // layers 3,4
    for (int L = 3; L <= 4; ++L) {
        k_mm_bn<<<MM_NBLK, B, 0, stream>>>(aggbuf, bnsum, bnsq, gg[L - 1], bt[L - 1], W[L], hbuf, bnpart);
        k_gather<<<MM_NBLK, B, 0, stream>>>(cursor, bsum, eidx, dinv, hbuf, bb[L], aggbuf, bnpart);
        k_bn_reduce<<<1, B, 0, stream>>>(bnpart, bnsum, bnsq,
                                         (L == 4) ? pooled : nullptr, (L == 4) ? cnt : nullptr);
    }

    // fused finalize+BN+pool (segmented) + FC
    k_pool_bn<<<512, B, 0, stream>>>(aggbuf, bnsum, bnsq, gg[4], bt[4], batch, pooled, cnt);
    k_fc<<<NG, 128, 0, stream>>>(pooled, cnt, fw1, fb1, fw2, fb2, out);
}

// Round 9
// 335.180 us; speedup vs baseline: 1.5288x; 1.5288x over previous
//
#include <hip/hip_runtime.h>

#define NN 50000
#define NE 800000
#define NG 64
#define FD 64
#define BN_EPS 1e-5f
#define SCAN_B 256
#define NBIN 98            // ceil(50000/512)
#define BINCAP 12288
#define SCH 4096
#define SCH_NBLK ((NE + SCH - 1) / SCH)          // 196
#define INV_NN (1.0f / NN)
#define MM_NBLK ((NN + 3) / 4)                   // 12500

// ---------------- CSR build: binned two-pass ----------------
__global__ __launch_bounds__(256) void k_binscatter(const int* __restrict__ row,
                                                    const int* __restrict__ col,
                                                    int* __restrict__ gcnt,
                                                    int* __restrict__ bins) {
    __shared__ int stage[SCH];
    __shared__ int cnt[NBIN], off[NBIN + 1], cur[NBIN], gbase[NBIN];
    int t = threadIdx.x;
    int e0 = blockIdx.x * SCH;
    int nk = NE - e0; if (nk > SCH) nk = SCH;
    if (nk <= 0) return;
    for (int b = t; b < NBIN; b += 256) cnt[b] = 0;
    __syncthreads();
    for (int k = t; k < nk; k += 256) {
        int c = col[e0 + k];
        atomicAdd(&cnt[c >> 9], 1);
    }
    __syncthreads();
    if (t == 0) {
        int run = 0;
        for (int b = 0; b < NBIN; ++b) { off[b] = run; run += cnt[b]; }
        off[NBIN] = run;
    }
    __syncthreads();
    if (t < NBIN) {
        cur[t] = off[t];
        gbase[t] = t * BINCAP + atomicAdd(&gcnt[t], cnt[t]);
    }
    __syncthreads();
    for (int k = t; k < nk; k += 256) {
        int c = col[e0 + k];
        int r = row[e0 + k];
        int b = c >> 9;
        int pos = atomicAdd(&cur[b], 1);
        stage[pos] = ((c & 511) << 16) | r;
    }
    __syncthreads();
    for (int k = t; k < nk; k += 256) {
        int lo = 0, hi = NBIN - 1;
        while (lo < hi) {
            int mid = (lo + hi + 1) >> 1;
            if (off[mid] <= k) lo = mid; else hi = mid - 1;
        }
        bins[gbase[lo] + (k - off[lo])] = stage[k];
    }
}

// per-bin degree hist + in-block scan + dinv + xd
__global__ __launch_bounds__(256) void k_binscan(const int* __restrict__ gcnt,
                                                 const int* __restrict__ bins,
                                                 const float* __restrict__ x,
                                                 int* __restrict__ cursor,
                                                 int* __restrict__ bsum,
                                                 float* __restrict__ dinv,
                                                 float* __restrict__ xd) {
    __shared__ int ldeg[512];
    __shared__ int psc[256];
    int b = blockIdx.x, t = threadIdx.x;
    for (int l = t; l < 512; l += 256) ldeg[l] = 0;
    __syncthreads();
    int nb = gcnt[b];
    const int* bp = bins + b * BINCAP;
    for (int k = t; k < nb; k += 256) atomicAdd(&ldeg[bp[k] >> 16], 1);
    __syncthreads();
    int d0 = ldeg[2 * t], d1 = ldeg[2 * t + 1];
    int pv = d0 + d1;
    psc[t] = pv;
    __syncthreads();
    for (int off = 1; off < 256; off <<= 1) {
        int u = (t >= off) ? psc[t - off] : 0;
        __syncthreads();
        psc[t] += u;
        __syncthreads();
    }
    int excl = psc[t] - pv;
    int base = b << 9;
    int i0 = base + 2 * t, i1 = i0 + 1;
    if (i0 < NN) {
        cursor[i0] = excl;
        float dv = rsqrtf((float)d0 + 1.0f);
        dinv[i0] = dv; xd[i0] = x[i0] * dv;
    }
    if (i1 < NN) {
        cursor[i1] = excl + d0;
        float dv = rsqrtf((float)d1 + 1.0f);
        dinv[i1] = dv; xd[i1] = x[i1] * dv;
    }
    if (t == 255) bsum[b] = psc[255];
}

// scan the 98 bin sums -> exclusive bin offsets; zero stats
__global__ __launch_bounds__(SCAN_B) void k_scan_top(int* __restrict__ bsum,
                                                     float* __restrict__ stats) {
    __shared__ int sh[SCAN_B];
    int t = threadIdx.x;
    if (t < 2) stats[t] = 0.0f;
    int v = (t < NBIN) ? bsum[t] : 0;
    sh[t] = v;
    __syncthreads();
    for (int off = 1; off < SCAN_B; off <<= 1) {
        int u = (t >= off) ? sh[t - off] : 0;
        __syncthreads();
        sh[t] += u;
        __syncthreads();
    }
    if (t < NBIN) bsum[t] = sh[t] - v;
}

// per-bin fill of eidx + fused layer-1 scalar propagation + stats
__global__ __launch_bounds__(256) void k_binfill_l1(const int* __restrict__ gcnt,
                                                    const int* __restrict__ bins,
                                                    const int* __restrict__ cursor,
                                                    const int* __restrict__ bsum,
                                                    int* __restrict__ eidx,
                                                    const float* __restrict__ xd,
                                                    const float* __restrict__ x,
                                                    const float* __restrict__ dinv,
                                                    float* __restrict__ s,
                                                    float* __restrict__ stats) {
    __shared__ int lstart[512], lcur[512];
    __shared__ float ls[256], lq[256];
    int b = blockIdx.x, t = threadIdx.x;
    int base = b << 9;
    int bofs = bsum[b];
    for (int l = t; l < 512; l += 256) {
        int i = base + l;
        int st = (i < NN) ? cursor[i] + bofs : 0;
        lstart[l] = st; lcur[l] = st;
    }
    __syncthreads();
    int nb = gcnt[b];
    const int* bp = bins + b * BINCAP;
    for (int k = t; k < nb; k += 256) {
        int v = bp[k];
        int pos = atomicAdd(&lcur[v >> 16], 1);
        eidx[pos] = v & 0xFFFF;
    }
    __syncthreads();
    float a = 0.0f, q = 0.0f;
    #pragma unroll
    for (int half = 0; half < 2; ++half) {
        int l = t + half * 256;
        int i = base + l;
        if (i < NN) {
            float acc = 0.0f;
            int e0 = lstart[l], e1 = lcur[l];
            for (int k = e0; k < e1; ++k) acc += xd[eidx[k]];
            float di = dinv[i];
            float sv = di * (acc + di * x[i]);
            s[i] = sv;
            a += sv; q += sv * sv;
        }
    }
    ls[t] = a; lq[t] = q;
    __syncthreads();
    for (int st = 128; st > 0; st >>= 1) {
        if (t < st) { ls[t] += ls[t + st]; lq[t] += lq[t + st]; }
        __syncthreads();
    }
    if (t == 0) { atomicAdd(&stats[0], ls[0]); atomicAdd(&stats[1], lq[0]); }
}

// ---------------- fused coeffs + activation + 64x64 matmul ----------------
__global__ __launch_bounds__(256) void k_mm_l1(const float* __restrict__ s,
                                               const float* __restrict__ stats,
                                               const float* __restrict__ W1,
                                               const float* __restrict__ g1,
                                               const float* __restrict__ bt1,
                                               const float* __restrict__ W,
                                               float* __restrict__ h) {
    __shared__ float Ws[64 * 64];
    __shared__ float xs[4 * 64];
    __shared__ float als[64], cls[64];
    int t = threadIdx.x;
    for (int k = t; k < 64 * 64; k += 256) Ws[k] = W[k];
    if (t < 64) {
        float mean = stats[0] * INV_NN;
        float var  = stats[1] * INV_NN - mean * mean;
        float w = W1[t];
        float rinv = rsqrtf(var * w * w + BN_EPS);
        float a = g1[t] * w * rinv;
        als[t] = a;
        cls[t] = bt1[t] - a * mean;
    }
    __syncthreads();
    int n0 = blockIdx.x * 4;
    int j = t & 63, n = t >> 6;
    int node = n0 + n;
    float sv = (node < NN) ? s[node] : 0.0f;
    xs[t] = fmaxf(als[j] * sv + cls[j], 0.0f);
    __syncthreads();
    if (node < NN) {
        float acc = 0.f;
        #pragma unroll
        for (int k = 0; k < 64; ++k) acc += xs[n * 64 + k] * Ws[k * 64 + j];
        h[node * 64 + j] = acc;
    }
}

__global__ __launch_bounds__(256) void k_mm_bn(const float* __restrict__ src,
                                               const float* __restrict__ bnsum,
                                               const float* __restrict__ bnsq,
                                               const float* __restrict__ g,
                                               const float* __restrict__ bt,
                                               const float* __restrict__ W,
                                               float* __restrict__ h) {
    __shared__ float Ws[64 * 64];
    __shared__ float xs[4 * 64];
    __shared__ float scl[64], shf[64];
    int t = threadIdx.x;
    for (int k = t; k < 64 * 64; k += 256) Ws[k] = W[k];
    if (t < 64) {
        float mean = bnsum[t] * INV_NN;
        float var  = bnsq[t] * INV_NN - mean * mean;
        float rinv = rsqrtf(var + BN_EPS);
        float sc = g[t] * rinv;
        scl[t] = sc;
        shf[t] = bt[t] - sc * mean;
    }
    __syncthreads();
    int n0 = blockIdx.x * 4;
    int j = t & 63, n = t >> 6;
    int node = n0 + n;
    int gidx = n0 * 64 + t;
    float v = (gidx < NN * 64) ? src[gidx] : 0.0f;
    xs[t] = fmaxf(scl[j] * v + shf[j], 0.0f);
    __syncthreads();
    if (node < NN) {
        float acc = 0.f;
        #pragma unroll
        for (int k = 0; k < 64; ++k) acc += xs[n * 64 + k] * Ws[k * 64 + j];
        h[node * 64 + j] = acc;
    }
}

// ---------------- CSR gather aggregation (self-loop + bias; zeros bn accumulators) ----------------
__global__ __launch_bounds__(256) void k_gather(const int* __restrict__ cursor,
                                                const int* __restrict__ bsum,
                                                const int* __restrict__ eidx,
                                                const float* __restrict__ dinv,
                                                const float* __restrict__ h,
                                                const float* __restrict__ b,
                                                float* __restrict__ agg,
                                                float* __restrict__ bnsumz,
                                                float* __restrict__ bnsqz) {
    if (blockIdx.x == 0) {
        int t = threadIdx.x;
        if (t < 64) bnsumz[t] = 0.0f;
        else if (t < 128) bnsqz[t - 64] = 0.0f;
    }
    int node = blockIdx.x * 4 + (threadIdx.x >> 6);
    if (node >= NN) return;
    int lane = threadIdx.x & 63;
    int eslot = lane >> 4;
    int fb = (lane & 15) << 2;
    int start = cursor[node] + bsum[node >> 9];
    int end = (node < NN - 1) ? cursor[node + 1] + bsum[(node + 1) >> 9] : NE;
    float4 acc0 = make_float4(0.f, 0.f, 0.f, 0.f);
    float4 acc1 = make_float4(0.f, 0.f, 0.f, 0.f);
    int e = start + eslot;
    for (; e + 4 < end; e += 8) {
        int r0 = eidx[e], r1 = eidx[e + 4];
        float dr0 = dinv[r0], dr1 = dinv[r1];
        const float4 h0 = *reinterpret_cast<const float4*>(&h[r0 * 64 + fb]);
        const float4 h1 = *reinterpret_cast<const float4*>(&h[r1 * 64 + fb]);
        acc0.x += h0.x * dr0; acc0.y += h0.y * dr0; acc0.z += h0.z * dr0; acc0.w += h0.w * dr0;
        acc1.x += h1.x * dr1; acc1.y += h1.y * dr1; acc1.z += h1.z * dr1; acc1.w += h1.w * dr1;
    }
    if (e < end) {
        int r = eidx[e];
        float dr = dinv[r];
        const float4 hv = *reinterpret_cast<const float4*>(&h[r * 64 + fb]);
        acc0.x += hv.x * dr; acc0.y += hv.y * dr; acc0.z += hv.z * dr; acc0.w += hv.w * dr;
    }
    acc0.x += acc1.x; acc0.y += acc1.y; acc0.z += acc1.z; acc0.w += acc1.w;
    acc0.x += __shfl_xor(acc0.x, 16); acc0.y += __shfl_xor(acc0.y, 16);
    acc0.z += __shfl_xor(acc0.z, 16); acc0.w += __shfl_xor(acc0.w, 16);
    acc0.x += __shfl_xor(acc0.x, 32); acc0.y += __shfl_xor(acc0.y, 32);
    acc0.z += __shfl_xor(acc0.z, 32); acc0.w += __shfl_xor(acc0.w, 32);
    if (lane < 16) {
        float dc = dinv[node];
        const float4 hv = *reinterpret_cast<const float4*>(&h[node * 64 + fb]);
        const float4 bv = *reinterpret_cast<const float4*>(&b[fb]);
        float4 o;
        o.x = dc * (acc0.x + dc * hv.x) + bv.x;
        o.y = dc * (acc0.y + dc * hv.y) + bv.y;
        o.z = dc * (acc0.z + dc * hv.z) + bv.z;
        o.w = dc * (acc0.w + dc * hv.w) + bv.w;
        *reinterpret_cast<float4*>(&agg[node * 64 + fb]) = o;
    }
}

// ---------------- batchnorm stats (optionally zeros pooled/cnt) ----------------
__global__ __launch_bounds__(256) void k_bn_stats(const float* __restrict__ agg,
                                                  float* __restrict__ bnsum, float* __restrict__ bnsq,
                                                  float* __restrict__ pooledz, float* __restrict__ cntz) {
    if (pooledz != nullptr && blockIdx.x == 0) {
        for (int k = threadIdx.x; k < 64 * 64; k += 256) pooledz[k] = 0.0f;
        if (threadIdx.x < 64) cntz[threadIdx.x] = 0.0f;
    }
    __shared__ float ls[256], lq[256];
    int j = threadIdx.x & 63, nl = threadIdx.x >> 6;
    float a = 0.f, b = 0.f;
    for (int i = blockIdx.x * 4 + nl; i < NN; i += gridDim.x * 4) {
        float v = agg[i * 64 + j]; a += v; b += v * v;
    }
    ls[threadIdx.x] = a; lq[threadIdx.x] = b; __syncthreads();
    if (threadIdx.x < 128) { ls[threadIdx.x] += ls[threadIdx.x + 128]; lq[threadIdx.x] += lq[threadIdx.x + 128]; }
    __syncthreads();
    if (threadIdx.x < 64) {
        atomicAdd(&bnsum[j], ls[threadIdx.x] + ls[threadIdx.x + 64]);
        atomicAdd(&bnsq[j],  lq[threadIdx.x] + lq[threadIdx.x + 64]);
    }
}

// ---------------- fused BN-finalize + BN + pooling (segmented) ----------------
__global__ __launch_bounds__(256) void k_pool_bn(const float* __restrict__ agg,
                                                 const float* __restrict__ bnsum,
                                                 const float* __restrict__ bnsq,
                                                 const float* __restrict__ g4,
                                                 const float* __restrict__ bt4,
                                                 const int* __restrict__ batch,
                                                 float* __restrict__ pooled,
                                                 float* __restrict__ cnt) {
    const int wpb = 4;
    int wave = blockIdx.x * wpb + (threadIdx.x >> 6);
    int lane = threadIdx.x & 63;
    const int nwaves = gridDim.x * wpb;
    int chunk = (NN + nwaves - 1) / nwaves;
    int i0 = wave * chunk;
    int i1 = i0 + chunk; if (i1 > NN) i1 = NN;
    if (i0 >= NN) return;
    float mean = bnsum[lane] * INV_NN;
    float var  = bnsq[lane] * INV_NN - mean * mean;
    float rinv = rsqrtf(var + BN_EPS);
    float sc = g4[lane] * rinv;
    float sh = bt4[lane] - sc * mean;
    float acc = 0.0f;
    int curb = batch[i0];
    int runlen = 0;
    for (int i = i0; i < i1; ++i) {
        int b = batch[i];
        if (b != curb) {
            atomicAdd(&pooled[curb * 64 + lane], acc);
            if (lane == 0) atomicAdd(&cnt[curb], (float)runlen);
            acc = 0.0f; runlen = 0; curb = b;
        }
        acc += fmaxf(sc * agg[i * 64 + lane] + sh, 0.0f);
        ++runlen;
    }
    atomicAdd(&pooled[curb * 64 + lane], acc);
    if (lane == 0) atomicAdd(&cnt[curb], (float)runlen);
}

__global__ __launch_bounds__(128) void k_fc(const float* __restrict__ pooled, const float* __restrict__ cnt,
                                            const float* __restrict__ fw1, const float* __restrict__ fb1,
                                            const float* __restrict__ fw2, const float* __restrict__ fb2,
                                            float* __restrict__ out) {
    __shared__ float p[64], hsh[128];
    int g = blockIdx.x, t = threadIdx.x;
    if (t < 64) {
        float c = cnt[g]; c = c < 1.f ? 1.f : c;
        p[t] = pooled[g * 64 + t] / c;
    }
    __syncthreads();
    float acc = fb1[t];
    #pragma unroll 8
    for (int k = 0; k < 64; ++k) acc += p[k] * fw1[t * 64 + k];
    hsh[t] = fmaxf(acc, 0.f);
    __syncthreads();
    if (t < 10) {
        float o = fb2[t];
        #pragma unroll 8
        for (int k = 0; k < 128; ++k) o += hsh[k] * fw2[t * 128 + k];
        out[g * 10 + t] = o;
    }
}

// ---------------- launch ----------------
extern "C" void kernel_launch(void* const* d_in, const int* in_sizes, int n_in,
                              void* d_out, int out_size, void* d_ws, size_t ws_size,
                              hipStream_t stream) {
    const float* x   = (const float*)d_in[0];
    const int* ei    = (const int*)d_in[1];
    const int* batch = (const int*)d_in[2];
    const float* W[5]  = {nullptr, (const float*)d_in[3],  (const float*)d_in[7],
                                   (const float*)d_in[11], (const float*)d_in[15]};
    const float* bb[5] = {nullptr, (const float*)d_in[4],  (const float*)d_in[8],
                                   (const float*)d_in[12], (const float*)d_in[16]};
    const float* gg[5] = {nullptr, (const float*)d_in[5],  (const float*)d_in[9],
                                   (const float*)d_in[13], (const float*)d_in[17]};
    const float* bt[5] = {nullptr, (const float*)d_in[6],  (const float*)d_in[10],
                                   (const float*)d_in[14], (const float*)d_in[18]};
    const float* fw1 = (const float*)d_in[19];
    const float* fb1 = (const float*)d_in[20];
    const float* fw2 = (const float*)d_in[21];
    const float* fb2 = (const float*)d_in[22];
    float* out = (float*)d_out;

    const int* row = ei;
    const int* col = ei + NE;

    float* ws = (float*)d_ws;
    int*   cursor  = (int*)ws;              // N
    int*   eidx    = (int*)(ws + 50000);    // E
    float* dinv    = ws + 850000;           // N
    float* xd      = ws + 900000;           // N
    int*   bsum    = (int*)(ws + 950000);   // NBIN
    float* s       = ws + 951000;           // N
    float* stats   = ws + 1001008;          // 2
    float* bnsum   = ws + 1001072;          // 64
    float* bnsq    = ws + 1001136;          // 64
    float* pooled  = ws + 1001360;          // 64*64
    float* cnt     = ws + 1005456;          // 64
    int*   gcnt    = (int*)(ws + 1056000);  // NBIN
    float* hbuf    = ws + 1100000;          // N*64 (bins alias pre-layer2)
    int*   bins    = (int*)(ws + 1100000);  // NBIN*BINCAP ints
    float* aggbuf  = ws + 4300000;          // N*64

    const int B = 256;

    // CSR build (binned) + dinv + xd
    hipMemsetAsync(gcnt, 0, NBIN * sizeof(int), stream);
    k_binscatter<<<SCH_NBLK, B, 0, stream>>>(row, col, gcnt, bins);
    k_binscan<<<NBIN, B, 0, stream>>>(gcnt, bins, x, cursor, bsum, dinv, xd);
    k_scan_top<<<1, SCAN_B, 0, stream>>>(bsum, stats);
    // fill eidx + layer-1 scalar propagation + stats
    k_binfill_l1<<<NBIN, B, 0, stream>>>(gcnt, bins, cursor, bsum, eidx, xd, x, dinv, s, stats);

    // layer 2
    k_mm_l1<<<MM_NBLK, B, 0, stream>>>(s, stats, W[1], gg[1], bt[1], W[2], hbuf);
    k_gather<<<MM_NBLK, B, 0, stream>>>(cursor, bsum, eidx, dinv, hbuf, bb[2], aggbuf, bnsum, bnsq);
    k_bn_stats<<<512, B, 0, stream>>>(aggbuf, bnsum, bnsq, nullptr, nullptr);

    // layers 3,4
    for (int L = 3; L <= 4; ++L) {
        k_mm_bn<<<MM_NBLK, B, 0, stream>>>(aggbuf, bnsum, bnsq, gg[L - 1], bt[L - 1], W[L], hbuf);
        k_gather<<<MM_NBLK, B, 0, stream>>>(cursor, bsum, eidx, dinv, hbuf, bb[L], aggbuf, bnsum, bnsq);
        k_bn_stats<<<512, B, 0, stream>>>(aggbuf, bnsum, bnsq,
                                          (L == 4) ? pooled : nullptr, (L == 4) ? cnt : nullptr);
    }

    // fused finalize+BN+pool (segmented) + FC
    k_pool_bn<<<512, B, 0, stream>>>(aggbuf, bnsum, bnsq, gg[4], bt[4], batch, pooled, cnt);
    k_fc<<<NG, 128, 0, stream>>>(pooled, cnt, fw1, fb1, fw2, fb2, out);
}

// Round 10
// 322.922 us; speedup vs baseline: 1.5868x; 1.0380x over previous
//
#include <hip/hip_runtime.h>
#include <hip/hip_fp16.h>

#define NN 50000
#define NE 800000
#define NG 64
#define FD 64
#define BN_EPS 1e-5f
#define SCAN_B 256
#define NBIN 98            // ceil(50000/512)
#define BINCAP 12288
#define SCH 4096
#define SCH_NBLK ((NE + SCH - 1) / SCH)          // 196
#define INV_NN (1.0f / NN)
#define MM_NBLK ((NN + 3) / 4)                   // 12500

// ---------------- CSR build: binned two-pass ----------------
__global__ __launch_bounds__(256) void k_binscatter(const int* __restrict__ row,
                                                    const int* __restrict__ col,
                                                    int* __restrict__ gcnt,
                                                    int* __restrict__ bins) {
    __shared__ int stage[SCH];
    __shared__ unsigned char stageb[SCH];
    __shared__ int cnt[NBIN], off[NBIN], cur[NBIN], gbase[NBIN];
    int t = threadIdx.x;
    int e0 = blockIdx.x * SCH;
    int nk = NE - e0; if (nk > SCH) nk = SCH;
    if (nk <= 0) return;
    for (int b = t; b < NBIN; b += 256) cnt[b] = 0;
    __syncthreads();
    for (int k = t; k < nk; k += 256) {
        int c = col[e0 + k];
        atomicAdd(&cnt[c >> 9], 1);
    }
    __syncthreads();
    if (t == 0) {
        int run = 0;
        for (int b = 0; b < NBIN; ++b) { off[b] = run; run += cnt[b]; }
    }
    __syncthreads();
    if (t < NBIN) {
        cur[t] = off[t];
        gbase[t] = t * BINCAP + atomicAdd(&gcnt[t], cnt[t]);
    }
    __syncthreads();
    for (int k = t; k < nk; k += 256) {
        int c = col[e0 + k];
        int r = row[e0 + k];
        int b = c >> 9;
        int pos = atomicAdd(&cur[b], 1);
        stage[pos] = ((c & 511) << 16) | r;
        stageb[pos] = (unsigned char)b;
    }
    __syncthreads();
    for (int k = t; k < nk; k += 256) {
        int b = stageb[k];
        bins[gbase[b] + (k - off[b])] = stage[k];
    }
}

// per-bin degree hist + in-block scan + dinv + xd
__global__ __launch_bounds__(256) void k_binscan(const int* __restrict__ gcnt,
                                                 const int* __restrict__ bins,
                                                 const float* __restrict__ x,
                                                 int* __restrict__ cursor,
                                                 int* __restrict__ bsum,
                                                 float* __restrict__ dinv,
                                                 float* __restrict__ xd) {
    __shared__ int ldeg[512];
    __shared__ int psc[256];
    int b = blockIdx.x, t = threadIdx.x;
    for (int l = t; l < 512; l += 256) ldeg[l] = 0;
    __syncthreads();
    int nb = gcnt[b];
    const int* bp = bins + b * BINCAP;
    for (int k = t; k < nb; k += 256) atomicAdd(&ldeg[bp[k] >> 16], 1);
    __syncthreads();
    int d0 = ldeg[2 * t], d1 = ldeg[2 * t + 1];
    int pv = d0 + d1;
    psc[t] = pv;
    __syncthreads();
    for (int off = 1; off < 256; off <<= 1) {
        int u = (t >= off) ? psc[t - off] : 0;
        __syncthreads();
        psc[t] += u;
        __syncthreads();
    }
    int excl = psc[t] - pv;
    int base = b << 9;
    int i0 = base + 2 * t, i1 = i0 + 1;
    if (i0 < NN) {
        cursor[i0] = excl;
        float dv = rsqrtf((float)d0 + 1.0f);
        dinv[i0] = dv; xd[i0] = x[i0] * dv;
    }
    if (i1 < NN) {
        cursor[i1] = excl + d0;
        float dv = rsqrtf((float)d1 + 1.0f);
        dinv[i1] = dv; xd[i1] = x[i1] * dv;
    }
    if (t == 255) bsum[b] = psc[255];
}

// scan the 98 bin sums -> exclusive bin offsets; zero stats
__global__ __launch_bounds__(SCAN_B) void k_scan_top(int* __restrict__ bsum,
                                                     float* __restrict__ stats) {
    __shared__ int sh[SCAN_B];
    int t = threadIdx.x;
    if (t < 2) stats[t] = 0.0f;
    int v = (t < NBIN) ? bsum[t] : 0;
    sh[t] = v;
    __syncthreads();
    for (int off = 1; off < SCAN_B; off <<= 1) {
        int u = (t >= off) ? sh[t - off] : 0;
        __syncthreads();
        sh[t] += u;
        __syncthreads();
    }
    if (t < NBIN) bsum[t] = sh[t] - v;
}

// per-bin fill of eidx + fused layer-1 scalar propagation + stats
__global__ __launch_bounds__(256) void k_binfill_l1(const int* __restrict__ gcnt,
                                                    const int* __restrict__ bins,
                                                    const int* __restrict__ cursor,
                                                    const int* __restrict__ bsum,
                                                    int* __restrict__ eidx,
                                                    const float* __restrict__ xd,
                                                    const float* __restrict__ x,
                                                    const float* __restrict__ dinv,
                                                    float* __restrict__ s,
                                                    float* __restrict__ stats) {
    __shared__ int lstart[512], lcur[512];
    __shared__ float ls[256], lq[256];
    int b = blockIdx.x, t = threadIdx.x;
    int base = b << 9;
    int bofs = bsum[b];
    for (int l = t; l < 512; l += 256) {
        int i = base + l;
        int st = (i < NN) ? cursor[i] + bofs : 0;
        lstart[l] = st; lcur[l] = st;
    }
    __syncthreads();
    int nb = gcnt[b];
    const int* bp = bins + b * BINCAP;
    for (int k = t; k < nb; k += 256) {
        int v = bp[k];
        int pos = atomicAdd(&lcur[v >> 16], 1);
        eidx[pos] = v & 0xFFFF;
    }
    __syncthreads();
    float a = 0.0f, q = 0.0f;
    #pragma unroll
    for (int half = 0; half < 2; ++half) {
        int l = t + half * 256;
        int i = base + l;
        if (i < NN) {
            float acc = 0.0f;
            int e0 = lstart[l], e1 = lcur[l];
            for (int k = e0; k < e1; ++k) acc += xd[eidx[k]];
            float di = dinv[i];
            float sv = di * (acc + di * x[i]);
            s[i] = sv;
            a += sv; q += sv * sv;
        }
    }
    ls[t] = a; lq[t] = q;
    __syncthreads();
    for (int st = 128; st > 0; st >>= 1) {
        if (t < st) { ls[t] += ls[t + st]; lq[t] += lq[t + st]; }
        __syncthreads();
    }
    if (t == 0) { atomicAdd(&stats[0], ls[0]); atomicAdd(&stats[1], lq[0]); }
}

// ---------------- fused coeffs + activation + 64x64 matmul (fp16 h out) ----------------
__global__ __launch_bounds__(256) void k_mm_l1(const float* __restrict__ s,
                                               const float* __restrict__ stats,
                                               const float* __restrict__ W1,
                                               const float* __restrict__ g1,
                                               const float* __restrict__ bt1,
                                               const float* __restrict__ W,
                                               __half* __restrict__ h) {
    __shared__ float Ws[64 * 64];
    __shared__ float xs[4 * 64];
    __shared__ float als[64], cls[64];
    int t = threadIdx.x;
    for (int k = t; k < 64 * 64; k += 256) Ws[k] = W[k];
    if (t < 64) {
        float mean = stats[0] * INV_NN;
        float var  = stats[1] * INV_NN - mean * mean;
        float w = W1[t];
        float rinv = rsqrtf(var * w * w + BN_EPS);
        float a = g1[t] * w * rinv;
        als[t] = a;
        cls[t] = bt1[t] - a * mean;
    }
    __syncthreads();
    int n0 = blockIdx.x * 4;
    int j = t & 63, n = t >> 6;
    int node = n0 + n;
    float sv = (node < NN) ? s[node] : 0.0f;
    xs[t] = fmaxf(als[j] * sv + cls[j], 0.0f);
    __syncthreads();
    if (node < NN) {
        float acc = 0.f;
        #pragma unroll
        for (int k = 0; k < 64; ++k) acc += xs[n * 64 + k] * Ws[k * 64 + j];
        h[node * 64 + j] = __float2half(acc);
    }
}

__global__ __launch_bounds__(256) void k_mm_bn(const float* __restrict__ src,
                                               const float* __restrict__ bnsum,
                                               const float* __restrict__ bnsq,
                                               const float* __restrict__ g,
                                               const float* __restrict__ bt,
                                               const float* __restrict__ W,
                                               __half* __restrict__ h) {
    __shared__ float Ws[64 * 64];
    __shared__ float xs[4 * 64];
    __shared__ float scl[64], shf[64];
    int t = threadIdx.x;
    for (int k = t; k < 64 * 64; k += 256) Ws[k] = W[k];
    if (t < 64) {
        float mean = bnsum[t] * INV_NN;
        float var  = bnsq[t] * INV_NN - mean * mean;
        float rinv = rsqrtf(var + BN_EPS);
        float sc = g[t] * rinv;
        scl[t] = sc;
        shf[t] = bt[t] - sc * mean;
    }
    __syncthreads();
    int n0 = blockIdx.x * 4;
    int j = t & 63, n = t >> 6;
    int node = n0 + n;
    int gidx = n0 * 64 + t;
    float v = (gidx < NN * 64) ? src[gidx] : 0.0f;
    xs[t] = fmaxf(scl[j] * v + shf[j], 0.0f);
    __syncthreads();
    if (node < NN) {
        float acc = 0.f;
        #pragma unroll
        for (int k = 0; k < 64; ++k) acc += xs[n * 64 + k] * Ws[k * 64 + j];
        h[node * 64 + j] = __float2half(acc);
    }
}

// ---------------- CSR gather aggregation (fp16 h in; self-loop + bias; zeros bn accum) ----------------
__global__ __launch_bounds__(256) void k_gather(const int* __restrict__ cursor,
                                                const int* __restrict__ bsum,
                                                const int* __restrict__ eidx,
                                                const float* __restrict__ dinv,
                                                const __half* __restrict__ h,
                                                const float* __restrict__ b,
                                                float* __restrict__ agg,
                                                float* __restrict__ bnsumz,
                                                float* __restrict__ bnsqz) {
    if (blockIdx.x == 0) {
        int t = threadIdx.x;
        if (t < 64) bnsumz[t] = 0.0f;
        else if (t < 128) bnsqz[t - 64] = 0.0f;
    }
    int node = blockIdx.x * 4 + (threadIdx.x >> 6);
    if (node >= NN) return;
    int lane = threadIdx.x & 63;
    int eslot = lane >> 4;
    int fb = (lane & 15) << 2;
    int start = cursor[node] + bsum[node >> 9];
    int end = (node < NN - 1) ? cursor[node + 1] + bsum[(node + 1) >> 9] : NE;
    float4 acc0 = make_float4(0.f, 0.f, 0.f, 0.f);
    float4 acc1 = make_float4(0.f, 0.f, 0.f, 0.f);
    int e = start + eslot;
    for (; e + 4 < end; e += 8) {
        int r0 = eidx[e], r1 = eidx[e + 4];
        float dr0 = dinv[r0], dr1 = dinv[r1];
        uint2 u0 = *reinterpret_cast<const uint2*>(&h[r0 * 64 + fb]);
        uint2 u1 = *reinterpret_cast<const uint2*>(&h[r1 * 64 + fb]);
        float2 a01 = __half22float2(*reinterpret_cast<__half2*>(&u0.x));
        float2 a23 = __half22float2(*reinterpret_cast<__half2*>(&u0.y));
        float2 b01 = __half22float2(*reinterpret_cast<__half2*>(&u1.x));
        float2 b23 = __half22float2(*reinterpret_cast<__half2*>(&u1.y));
        acc0.x += a01.x * dr0; acc0.y += a01.y * dr0; acc0.z += a23.x * dr0; acc0.w += a23.y * dr0;
        acc1.x += b01.x * dr1; acc1.y += b01.y * dr1; acc1.z += b23.x * dr1; acc1.w += b23.y * dr1;
    }
    if (e < end) {
        int r = eidx[e];
        float dr = dinv[r];
        uint2 u0 = *reinterpret_cast<const uint2*>(&h[r * 64 + fb]);
        float2 a01 = __half22float2(*reinterpret_cast<__half2*>(&u0.x));
        float2 a23 = __half22float2(*reinterpret_cast<__half2*>(&u0.y));
        acc0.x += a01.x * dr; acc0.y += a01.y * dr; acc0.z += a23.x * dr; acc0.w += a23.y * dr;
    }
    acc0.x += acc1.x; acc0.y += acc1.y; acc0.z += acc1.z; acc0.w += acc1.w;
    acc0.x += __shfl_xor(acc0.x, 16); acc0.y += __shfl_xor(acc0.y, 16);
    acc0.z += __shfl_xor(acc0.z, 16); acc0.w += __shfl_xor(acc0.w, 16);
    acc0.x += __shfl_xor(acc0.x, 32); acc0.y += __shfl_xor(acc0.y, 32);
    acc0.z += __shfl_xor(acc0.z, 32); acc0.w += __shfl_xor(acc0.w, 32);
    if (lane < 16) {
        float dc = dinv[node];
        uint2 u0 = *reinterpret_cast<const uint2*>(&h[node * 64 + fb]);
        float2 s01 = __half22float2(*reinterpret_cast<__half2*>(&u0.x));
        float2 s23 = __half22float2(*reinterpret_cast<__half2*>(&u0.y));
        const float4 bv = *reinterpret_cast<const float4*>(&b[fb]);
        float4 o;
        o.x = dc * (acc0.x + dc * s01.x) + bv.x;
        o.y = dc * (acc0.y + dc * s01.y) + bv.y;
        o.z = dc * (acc0.z + dc * s23.x) + bv.z;
        o.w = dc * (acc0.w + dc * s23.y) + bv.w;
        *reinterpret_cast<float4*>(&agg[node * 64 + fb]) = o;
    }
}

// ---------------- batchnorm stats (optionally zeros pooled/cnt) ----------------
__global__ __launch_bounds__(256) void k_bn_stats(const float* __restrict__ agg,
                                                  float* __restrict__ bnsum, float* __restrict__ bnsq,
                                                  float* __restrict__ pooledz, float* __restrict__ cntz) {
    if (pooledz != nullptr && blockIdx.x == 0) {
        for (int k = threadIdx.x; k < 64 * 64; k += 256) pooledz[k] = 0.0f;
        if (threadIdx.x < 64) cntz[threadIdx.x] = 0.0f;
    }
    __shared__ float ls[256], lq[256];
    int j = threadIdx.x & 63, nl = threadIdx.x >> 6;
    float a = 0.f, b = 0.f;
    for (int i = blockIdx.x * 4 + nl; i < NN; i += gridDim.x * 4) {
        float v = agg[i * 64 + j]; a += v; b += v * v;
    }
    ls[threadIdx.x] = a; lq[threadIdx.x] = b; __syncthreads();
    if (threadIdx.x < 128) { ls[threadIdx.x] += ls[threadIdx.x + 128]; lq[threadIdx.x] += lq[threadIdx.x + 128]; }
    __syncthreads();
    if (threadIdx.x < 64) {
        atomicAdd(&bnsum[j], ls[threadIdx.x] + ls[threadIdx.x + 64]);
        atomicAdd(&bnsq[j],  lq[threadIdx.x] + lq[threadIdx.x + 64]);
    }
}

// ---------------- fused BN-finalize + BN + pooling (segmented) ----------------
__global__ __launch_bounds__(256) void k_pool_bn(const float* __restrict__ agg,
                                                 const float* __restrict__ bnsum,
                                                 const float* __restrict__ bnsq,
                                                 const float* __restrict__ g4,
                                                 const float* __restrict__ bt4,
                                                 const int* __restrict__ batch,
                                                 float* __restrict__ pooled,
                                                 float* __restrict__ cnt) {
    const int wpb = 4;
    int wave = blockIdx.x * wpb + (threadIdx.x >> 6);
    int lane = threadIdx.x & 63;
    const int nwaves = gridDim.x * wpb;
    int chunk = (NN + nwaves - 1) / nwaves;
    int i0 = wave * chunk;
    int i1 = i0 + chunk; if (i1 > NN) i1 = NN;
    if (i0 >= NN) return;
    float mean = bnsum[lane] * INV_NN;
    float var  = bnsq[lane] * INV_NN - mean * mean;
    float rinv = rsqrtf(var + BN_EPS);
    float sc = g4[lane] * rinv;
    float sh = bt4[lane] - sc * mean;
    float acc = 0.0f;
    int curb = batch[i0];
    int runlen = 0;
    for (int i = i0; i < i1; ++i) {
        int b = batch[i];
        if (b != curb) {
            atomicAdd(&pooled[curb * 64 + lane], acc);
            if (lane == 0) atomicAdd(&cnt[curb], (float)runlen);
            acc = 0.0f; runlen = 0; curb = b;
        }
        acc += fmaxf(sc * agg[i * 64 + lane] + sh, 0.0f);
        ++runlen;
    }
    atomicAdd(&pooled[curb * 64 + lane], acc);
    if (lane == 0) atomicAdd(&cnt[curb], (float)runlen);
}

__global__ __launch_bounds__(128) void k_fc(const float* __restrict__ pooled, const float* __restrict__ cnt,
                                            const float* __restrict__ fw1, const float* __restrict__ fb1,
                                            const float* __restrict__ fw2, const float* __restrict__ fb2,
                                            float* __restrict__ out) {
    __shared__ float p[64], hsh[128];
    int g = blockIdx.x, t = threadIdx.x;
    if (t < 64) {
        float c = cnt[g]; c = c < 1.f ? 1.f : c;
        p[t] = pooled[g * 64 + t] / c;
    }
    __syncthreads();
    float acc = fb1[t];
    #pragma unroll 8
    for (int k = 0; k < 64; ++k) acc += p[k] * fw1[t * 64 + k];
    hsh[t] = fmaxf(acc, 0.f);
    __syncthreads();
    if (t < 10) {
        float o = fb2[t];
        #pragma unroll 8
        for (int k = 0; k < 128; ++k) o += hsh[k] * fw2[t * 128 + k];
        out[g * 10 + t] = o;
    }
}

// ---------------- launch ----------------
extern "C" void kernel_launch(void* const* d_in, const int* in_sizes, int n_in,
                              void* d_out, int out_size, void* d_ws, size_t ws_size,
                              hipStream_t stream) {
    const float* x   = (const float*)d_in[0];
    const int* ei    = (const int*)d_in[1];
    const int* batch = (const int*)d_in[2];
    const float* W[5]  = {nullptr, (const float*)d_in[3],  (const float*)d_in[7],
                                   (const float*)d_in[11], (const float*)d_in[15]};
    const float* bb[5] = {nullptr, (const float*)d_in[4],  (const float*)d_in[8],
                                   (const float*)d_in[12], (const float*)d_in[16]};
    const float* gg[5] = {nullptr, (const float*)d_in[5],  (const float*)d_in[9],
                                   (const float*)d_in[13], (const float*)d_in[17]};
    const float* bt[5] = {nullptr, (const float*)d_in[6],  (const float*)d_in[10],
                                   (const float*)d_in[14], (const float*)d_in[18]};
    const float* fw1 = (const float*)d_in[19];
    const float* fb1 = (const float*)d_in[20];
    const float* fw2 = (const float*)d_in[21];
    const float* fb2 = (const float*)d_in[22];
    float* out = (float*)d_out;

    const int* row = ei;
    const int* col = ei + NE;

    float* ws = (float*)d_ws;
    int*   cursor  = (int*)ws;              // N
    int*   eidx    = (int*)(ws + 50000);    // E
    float* dinv    = ws + 850000;           // N
    float* xd      = ws + 900000;           // N
    int*   bsum    = (int*)(ws + 950000);   // NBIN
    float* s       = ws + 951000;           // N
    float* stats   = ws + 1001008;          // 2
    float* bnsum   = ws + 1001072;          // 64
    float* bnsq    = ws + 1001136;          // 64
    float* pooled  = ws + 1001360;          // 64*64
    float* cnt     = ws + 1005456;          // 64
    int*   gcnt    = (int*)(ws + 1056000);  // NBIN
    __half* hbuf   = (__half*)(ws + 1100000); // N*64 halves = 1.6M float slots (bins alias pre-layer2)
    int*   bins    = (int*)(ws + 1100000);  // NBIN*BINCAP ints = 1.204M float slots
    float* aggbuf  = ws + 4300000;          // N*64

    const int B = 256;

    // CSR build (binned) + dinv + xd
    hipMemsetAsync(gcnt, 0, NBIN * sizeof(int), stream);
    k_binscatter<<<SCH_NBLK, B, 0, stream>>>(row, col, gcnt, bins);
    k_binscan<<<NBIN, B, 0, stream>>>(gcnt, bins, x, cursor, bsum, dinv, xd);
    k_scan_top<<<1, SCAN_B, 0, stream>>>(bsum, stats);
    // fill eidx + layer-1 scalar propagation + stats
    k_binfill_l1<<<NBIN, B, 0, stream>>>(gcnt, bins, cursor, bsum, eidx, xd, x, dinv, s, stats);

    // layer 2
    k_mm_l1<<<MM_NBLK, B, 0, stream>>>(s, stats, W[1], gg[1], bt[1], W[2], hbuf);
    k_gather<<<MM_NBLK, B, 0, stream>>>(cursor, bsum, eidx, dinv, hbuf, bb[2], aggbuf, bnsum, bnsq);
    k_bn_stats<<<512, B, 0, stream>>>(aggbuf, bnsum, bnsq, nullptr, nullptr);

    // layers 3,4
    for (int L = 3; L <= 4; ++L) {
        k_mm_bn<<<MM_NBLK, B, 0, stream>>>(aggbuf, bnsum, bnsq, gg[L - 1], bt[L - 1], W[L], hbuf);
        k_gather<<<MM_NBLK, B, 0, stream>>>(cursor, bsum, eidx, dinv, hbuf, bb[L], aggbuf, bnsum, bnsq);
        k_bn_stats<<<512, B, 0, stream>>>(aggbuf, bnsum, bnsq,
                                          (L == 4) ? pooled : nullptr, (L == 4) ? cnt : nullptr);
    }

    // fused finalize+BN+pool (segmented) + FC
    k_pool_bn<<<512, B, 0, stream>>>(aggbuf, bnsum, bnsq, gg[4], bt[4], batch, pooled, cnt);
    k_fc<<<NG, 128, 0, stream>>>(pooled, cnt, fw1, fb1, fw2, fb2, out);
}

// Round 11
// 306.205 us; speedup vs baseline: 1.6734x; 1.0546x over previous
//
#include <hip/hip_runtime.h>
#include <hip/hip_fp16.h>

#define NN 50000
#define NE 800000
#define NG 64
#define FD 64
#define BN_EPS 1e-5f
#define SCAN_B 256
#define NBIN 98            // ceil(50000/512)
#define BINCAP 12288
#define SCH 4096
#define SCH_NBLK ((NE + SCH - 1) / SCH)          // 196
#define INV_NN (1.0f / NN)
#define MM_NBLK ((NN + 3) / 4)                   // 12500

// ---------------- CSR build: binned two-pass ----------------
__global__ __launch_bounds__(256) void k_binscatter(const int* __restrict__ row,
                                                    const int* __restrict__ col,
                                                    int* __restrict__ gcnt,
                                                    int* __restrict__ bins) {
    __shared__ int stage[SCH];
    __shared__ unsigned char stageb[SCH];
    __shared__ int cnt[NBIN], off[NBIN], cur[NBIN], gbase[NBIN];
    int t = threadIdx.x;
    int e0 = blockIdx.x * SCH;
    int nk = NE - e0; if (nk > SCH) nk = SCH;
    if (nk <= 0) return;
    for (int b = t; b < NBIN; b += 256) cnt[b] = 0;
    __syncthreads();
    for (int k = t; k < nk; k += 256) {
        int c = col[e0 + k];
        atomicAdd(&cnt[c >> 9], 1);
    }
    __syncthreads();
    if (t == 0) {
        int run = 0;
        for (int b = 0; b < NBIN; ++b) { off[b] = run; run += cnt[b]; }
    }
    __syncthreads();
    if (t < NBIN) {
        cur[t] = off[t];
        gbase[t] = t * BINCAP + atomicAdd(&gcnt[t], cnt[t]);
    }
    __syncthreads();
    for (int k = t; k < nk; k += 256) {
        int c = col[e0 + k];
        int r = row[e0 + k];
        int b = c >> 9;
        int pos = atomicAdd(&cur[b], 1);
        stage[pos] = ((c & 511) << 16) | r;
        stageb[pos] = (unsigned char)b;
    }
    __syncthreads();
    for (int k = t; k < nk; k += 256) {
        int b = stageb[k];
        bins[gbase[b] + (k - off[b])] = stage[k];
    }
}

// per-bin degree hist + in-block scan + dinv + xd
__global__ __launch_bounds__(256) void k_binscan(const int* __restrict__ gcnt,
                                                 const int* __restrict__ bins,
                                                 const float* __restrict__ x,
                                                 int* __restrict__ cursor,
                                                 int* __restrict__ bsum,
                                                 float* __restrict__ dinv,
                                                 float* __restrict__ xd) {
    __shared__ int ldeg[512];
    __shared__ int psc[256];
    int b = blockIdx.x, t = threadIdx.x;
    for (int l = t; l < 512; l += 256) ldeg[l] = 0;
    __syncthreads();
    int nb = gcnt[b];
    const int* bp = bins + b * BINCAP;
    for (int k = t; k < nb; k += 256) atomicAdd(&ldeg[bp[k] >> 16], 1);
    __syncthreads();
    int d0 = ldeg[2 * t], d1 = ldeg[2 * t + 1];
    int pv = d0 + d1;
    psc[t] = pv;
    __syncthreads();
    for (int off = 1; off < 256; off <<= 1) {
        int u = (t >= off) ? psc[t - off] : 0;
        __syncthreads();
        psc[t] += u;
        __syncthreads();
    }
    int excl = psc[t] - pv;
    int base = b << 9;
    int i0 = base + 2 * t, i1 = i0 + 1;
    if (i0 < NN) {
        cursor[i0] = excl;
        float dv = rsqrtf((float)d0 + 1.0f);
        dinv[i0] = dv; xd[i0] = x[i0] * dv;
    }
    if (i1 < NN) {
        cursor[i1] = excl + d0;
        float dv = rsqrtf((float)d1 + 1.0f);
        dinv[i1] = dv; xd[i1] = x[i1] * dv;
    }
    if (t == 255) bsum[b] = psc[255];
}

// scan the 98 bin sums -> exclusive bin offsets; zero stats
__global__ __launch_bounds__(SCAN_B) void k_scan_top(int* __restrict__ bsum,
                                                     float* __restrict__ stats) {
    __shared__ int sh[SCAN_B];
    int t = threadIdx.x;
    if (t < 2) stats[t] = 0.0f;
    int v = (t < NBIN) ? bsum[t] : 0;
    sh[t] = v;
    __syncthreads();
    for (int off = 1; off < SCAN_B; off <<= 1) {
        int u = (t >= off) ? sh[t - off] : 0;
        __syncthreads();
        sh[t] += u;
        __syncthreads();
    }
    if (t < NBIN) bsum[t] = sh[t] - v;
}

// per-bin fill of eidx + fused layer-1 scalar propagation + stats
__global__ __launch_bounds__(256) void k_binfill_l1(const int* __restrict__ gcnt,
                                                    const int* __restrict__ bins,
                                                    const int* __restrict__ cursor,
                                                    const int* __restrict__ bsum,
                                                    int* __restrict__ eidx,
                                                    const float* __restrict__ xd,
                                                    const float* __restrict__ x,
                                                    const float* __restrict__ dinv,
                                                    float* __restrict__ s,
                                                    float* __restrict__ stats) {
    __shared__ int lstart[512], lcur[512];
    __shared__ float ls[256], lq[256];
    int b = blockIdx.x, t = threadIdx.x;
    int base = b << 9;
    int bofs = bsum[b];
    for (int l = t; l < 512; l += 256) {
        int i = base + l;
        int st = (i < NN) ? cursor[i] + bofs : 0;
        lstart[l] = st; lcur[l] = st;
    }
    __syncthreads();
    int nb = gcnt[b];
    const int* bp = bins + b * BINCAP;
    for (int k = t; k < nb; k += 256) {
        int v = bp[k];
        int pos = atomicAdd(&lcur[v >> 16], 1);
        eidx[pos] = v & 0xFFFF;
    }
    __syncthreads();
    float a = 0.0f, q = 0.0f;
    #pragma unroll
    for (int half = 0; half < 2; ++half) {
        int l = t + half * 256;
        int i = base + l;
        if (i < NN) {
            float acc = 0.0f;
            int e0 = lstart[l], e1 = lcur[l];
            for (int k = e0; k < e1; ++k) acc += xd[eidx[k]];
            float di = dinv[i];
            float sv = di * (acc + di * x[i]);
            s[i] = sv;
            a += sv; q += sv * sv;
        }
    }
    ls[t] = a; lq[t] = q;
    __syncthreads();
    for (int st = 128; st > 0; st >>= 1) {
        if (t < st) { ls[t] += ls[t + st]; lq[t] += lq[t + st]; }
        __syncthreads();
    }
    if (t == 0) { atomicAdd(&stats[0], ls[0]); atomicAdd(&stats[1], lq[0]); }
}

// ---------------- fused coeffs + activation + 64x64 matmul (fp16 h' = h*dinv out) ----------------
__global__ __launch_bounds__(256) void k_mm_l1(const float* __restrict__ s,
                                               const float* __restrict__ stats,
                                               const float* __restrict__ W1,
                                               const float* __restrict__ g1,
                                               const float* __restrict__ bt1,
                                               const float* __restrict__ W,
                                               const float* __restrict__ dinv,
                                               __half* __restrict__ h) {
    __shared__ float Ws[64 * 64];
    __shared__ float xs[4 * 64];
    __shared__ float als[64], cls[64];
    int t = threadIdx.x;
    for (int k = t; k < 64 * 64; k += 256) Ws[k] = W[k];
    if (t < 64) {
        float mean = stats[0] * INV_NN;
        float var  = stats[1] * INV_NN - mean * mean;
        float w = W1[t];
        float rinv = rsqrtf(var * w * w + BN_EPS);
        float a = g1[t] * w * rinv;
        als[t] = a;
        cls[t] = bt1[t] - a * mean;
    }
    __syncthreads();
    int n0 = blockIdx.x * 4;
    int j = t & 63, n = t >> 6;
    int node = n0 + n;
    float sv = (node < NN) ? s[node] : 0.0f;
    xs[t] = fmaxf(als[j] * sv + cls[j], 0.0f);
    __syncthreads();
    if (node < NN) {
        float acc = 0.f;
        #pragma unroll
        for (int k = 0; k < 64; ++k) acc += xs[n * 64 + k] * Ws[k * 64 + j];
        h[node * 64 + j] = __float2half(acc * dinv[node]);
    }
}

__global__ __launch_bounds__(256) void k_mm_bn(const float* __restrict__ src,
                                               const float* __restrict__ bnsum,
                                               const float* __restrict__ bnsq,
                                               const float* __restrict__ g,
                                               const float* __restrict__ bt,
                                               const float* __restrict__ W,
                                               const float* __restrict__ dinv,
                                               __half* __restrict__ h) {
    __shared__ float Ws[64 * 64];
    __shared__ float xs[4 * 64];
    __shared__ float scl[64], shf[64];
    int t = threadIdx.x;
    for (int k = t; k < 64 * 64; k += 256) Ws[k] = W[k];
    if (t < 64) {
        float mean = bnsum[t] * INV_NN;
        float var  = bnsq[t] * INV_NN - mean * mean;
        float rinv = rsqrtf(var + BN_EPS);
        float sc = g[t] * rinv;
        scl[t] = sc;
        shf[t] = bt[t] - sc * mean;
    }
    __syncthreads();
    int n0 = blockIdx.x * 4;
    int j = t & 63, n = t >> 6;
    int node = n0 + n;
    int gidx = n0 * 64 + t;
    float v = (gidx < NN * 64) ? src[gidx] : 0.0f;
    xs[t] = fmaxf(scl[j] * v + shf[j], 0.0f);
    __syncthreads();
    if (node < NN) {
        float acc = 0.f;
        #pragma unroll
        for (int k = 0; k < 64; ++k) acc += xs[n * 64 + k] * Ws[k * 64 + j];
        h[node * 64 + j] = __float2half(acc * dinv[node]);
    }
}

// ---------------- CSR gather aggregation ----------------
// h is pre-scaled by dinv[src]; agg[c] = dinv[c]*(sum_r h'[r] + h'[c]) + b
// 8 edge slots x 8 lanes x uint4 (8 halves); x2 unroll -> 16 rows in flight
__global__ __launch_bounds__(256) void k_gather(const int* __restrict__ cursor,
                                                const int* __restrict__ bsum,
                                                const int* __restrict__ eidx,
                                                const float* __restrict__ dinv,
                                                const __half* __restrict__ h,
                                                const float* __restrict__ b,
                                                float* __restrict__ agg,
                                                float* __restrict__ bnsumz,
                                                float* __restrict__ bnsqz) {
    if (blockIdx.x == 0) {
        int tt = threadIdx.x;
        if (tt < 64) bnsumz[tt] = 0.0f;
        else if (tt < 128) bnsqz[tt - 64] = 0.0f;
    }
    int node = blockIdx.x * 4 + (threadIdx.x >> 6);
    if (node >= NN) return;
    int lane = threadIdx.x & 63;
    int eslot = lane >> 3;          // 0..7
    int fb = (lane & 7) << 3;       // feature base in halves: 0,8,...,56
    int start = cursor[node] + bsum[node >> 9];
    int end = (node < NN - 1) ? cursor[node + 1] + bsum[(node + 1) >> 9] : NE;
    float a0 = 0.f, a1 = 0.f, a2 = 0.f, a3 = 0.f, a4 = 0.f, a5 = 0.f, a6 = 0.f, a7 = 0.f;
    float c0 = 0.f, c1 = 0.f, c2 = 0.f, c3 = 0.f, c4 = 0.f, c5 = 0.f, c6 = 0.f, c7 = 0.f;
    int e = start + eslot;
    for (; e + 8 < end; e += 16) {
        int r0 = eidx[e], r1 = eidx[e + 8];
        uint4 u = *reinterpret_cast<const uint4*>(&h[(r0 << 6) + fb]);
        uint4 v = *reinterpret_cast<const uint4*>(&h[(r1 << 6) + fb]);
        float2 p;
        p = __half22float2(*reinterpret_cast<__half2*>(&u.x)); a0 += p.x; a1 += p.y;
        p = __half22float2(*reinterpret_cast<__half2*>(&u.y)); a2 += p.x; a3 += p.y;
        p = __half22float2(*reinterpret_cast<__half2*>(&u.z)); a4 += p.x; a5 += p.y;
        p = __half22float2(*reinterpret_cast<__half2*>(&u.w)); a6 += p.x; a7 += p.y;
        p = __half22float2(*reinterpret_cast<__half2*>(&v.x)); c0 += p.x; c1 += p.y;
        p = __half22float2(*reinterpret_cast<__half2*>(&v.y)); c2 += p.x; c3 += p.y;
        p = __half22float2(*reinterpret_cast<__half2*>(&v.z)); c4 += p.x; c5 += p.y;
        p = __half22float2(*reinterpret_cast<__half2*>(&v.w)); c6 += p.x; c7 += p.y;
    }
    if (e < end) {
        int r = eidx[e];
        uint4 u = *reinterpret_cast<const uint4*>(&h[(r << 6) + fb]);
        float2 p;
        p = __half22float2(*reinterpret_cast<__half2*>(&u.x)); a0 += p.x; a1 += p.y;
        p = __half22float2(*reinterpret_cast<__half2*>(&u.y)); a2 += p.x; a3 += p.y;
        p = __half22float2(*reinterpret_cast<__half2*>(&u.z)); a4 += p.x; a5 += p.y;
        p = __half22float2(*reinterpret_cast<__half2*>(&u.w)); a6 += p.x; a7 += p.y;
    }
    a0 += c0; a1 += c1; a2 += c2; a3 += c3; a4 += c4; a5 += c5; a6 += c6; a7 += c7;
    // reduce across 8 slots (lane bits 3,4,5)
    #pragma unroll
    for (int d = 8; d <= 32; d <<= 1) {
        a0 += __shfl_xor(a0, d); a1 += __shfl_xor(a1, d);
        a2 += __shfl_xor(a2, d); a3 += __shfl_xor(a3, d);
        a4 += __shfl_xor(a4, d); a5 += __shfl_xor(a5, d);
        a6 += __shfl_xor(a6, d); a7 += __shfl_xor(a7, d);
    }
    if (eslot == 0) {   // lanes 0..7
        float dc = dinv[node];
        uint4 u = *reinterpret_cast<const uint4*>(&h[(node << 6) + fb]);
        float2 p;
        p = __half22float2(*reinterpret_cast<__half2*>(&u.x)); a0 += p.x; a1 += p.y;
        p = __half22float2(*reinterpret_cast<__half2*>(&u.y)); a2 += p.x; a3 += p.y;
        p = __half22float2(*reinterpret_cast<__half2*>(&u.z)); a4 += p.x; a5 += p.y;
        p = __half22float2(*reinterpret_cast<__half2*>(&u.w)); a6 += p.x; a7 += p.y;
        const float4 bv0 = *reinterpret_cast<const float4*>(&b[fb]);
        const float4 bv1 = *reinterpret_cast<const float4*>(&b[fb + 4]);
        float4 o0, o1;
        o0.x = dc * a0 + bv0.x; o0.y = dc * a1 + bv0.y;
        o0.z = dc * a2 + bv0.z; o0.w = dc * a3 + bv0.w;
        o1.x = dc * a4 + bv1.x; o1.y = dc * a5 + bv1.y;
        o1.z = dc * a6 + bv1.z; o1.w = dc * a7 + bv1.w;
        *reinterpret_cast<float4*>(&agg[node * 64 + fb]) = o0;
        *reinterpret_cast<float4*>(&agg[node * 64 + fb + 4]) = o1;
    }
}

// ---------------- batchnorm stats (optionally zeros pooled/cnt) ----------------
__global__ __launch_bounds__(256) void k_bn_stats(const float* __restrict__ agg,
                                                  float* __restrict__ bnsum, float* __restrict__ bnsq,
                                                  float* __restrict__ pooledz, float* __restrict__ cntz) {
    if (pooledz != nullptr && blockIdx.x == 0) {
        for (int k = threadIdx.x; k < 64 * 64; k += 256) pooledz[k] = 0.0f;
        if (threadIdx.x < 64) cntz[threadIdx.x] = 0.0f;
    }
    __shared__ float ls[256], lq[256];
    int j = threadIdx.x & 63, nl = threadIdx.x >> 6;
    float a = 0.f, b = 0.f;
    for (int i = blockIdx.x * 4 + nl; i < NN; i += gridDim.x * 4) {
        float v = agg[i * 64 + j]; a += v; b += v * v;
    }
    ls[threadIdx.x] = a; lq[threadIdx.x] = b; __syncthreads();
    if (threadIdx.x < 128) { ls[threadIdx.x] += ls[threadIdx.x + 128]; lq[threadIdx.x] += lq[threadIdx.x + 128]; }
    __syncthreads();
    if (threadIdx.x < 64) {
        atomicAdd(&bnsum[j], ls[threadIdx.x] + ls[threadIdx.x + 64]);
        atomicAdd(&bnsq[j],  lq[threadIdx.x] + lq[threadIdx.x + 64]);
    }
}

// ---------------- fused BN-finalize + BN + pooling (segmented) ----------------
__global__ __launch_bounds__(256) void k_pool_bn(const float* __restrict__ agg,
                                                 const float* __restrict__ bnsum,
                                                 const float* __restrict__ bnsq,
                                                 const float* __restrict__ g4,
                                                 const float* __restrict__ bt4,
                                                 const int* __restrict__ batch,
                                                 float* __restrict__ pooled,
                                                 float* __restrict__ cnt) {
    const int wpb = 4;
    int wave = blockIdx.x * wpb + (threadIdx.x >> 6);
    int lane = threadIdx.x & 63;
    const int nwaves = gridDim.x * wpb;
    int chunk = (NN + nwaves - 1) / nwaves;
    int i0 = wave * chunk;
    int i1 = i0 + chunk; if (i1 > NN) i1 = NN;
    if (i0 >= NN) return;
    float mean = bnsum[lane] * INV_NN;
    float var  = bnsq[lane] * INV_NN - mean * mean;
    float rinv = rsqrtf(var + BN_EPS);
    float sc = g4[lane] * rinv;
    float sh = bt4[lane] - sc * mean;
    float acc = 0.0f;
    int curb = batch[i0];
    int runlen = 0;
    for (int i = i0; i < i1; ++i) {
        int b = batch[i];
        if (b != curb) {
            atomicAdd(&pooled[curb * 64 + lane], acc);
            if (lane == 0) atomicAdd(&cnt[curb], (float)runlen);
            acc = 0.0f; runlen = 0; curb = b;
        }
        acc += fmaxf(sc * agg[i * 64 + lane] + sh, 0.0f);
        ++runlen;
    }
    atomicAdd(&pooled[curb * 64 + lane], acc);
    if (lane == 0) atomicAdd(&cnt[curb], (float)runlen);
}

__global__ __launch_bounds__(128) void k_fc(const float* __restrict__ pooled, const float* __restrict__ cnt,
                                            const float* __restrict__ fw1, const float* __restrict__ fb1,
                                            const float* __restrict__ fw2, const float* __restrict__ fb2,
                                            float* __restrict__ out) {
    __shared__ float p[64], hsh[128];
    int g = blockIdx.x, t = threadIdx.x;
    if (t < 64) {
        float c = cnt[g]; c = c < 1.f ? 1.f : c;
        p[t] = pooled[g * 64 + t] / c;
    }
    __syncthreads();
    float acc = fb1[t];
    #pragma unroll 8
    for (int k = 0; k < 64; ++k) acc += p[k] * fw1[t * 64 + k];
    hsh[t] = fmaxf(acc, 0.f);
    __syncthreads();
    if (t < 10) {
        float o = fb2[t];
        #pragma unroll 8
        for (int k = 0; k < 128; ++k) o += hsh[k] * fw2[t * 128 + k];
        out[g * 10 + t] = o;
    }
}

// ---------------- launch ----------------
extern "C" void kernel_launch(void* const* d_in, const int* in_sizes, int n_in,
                              void* d_out, int out_size, void* d_ws, size_t ws_size,
                              hipStream_t stream) {
    const float* x   = (const float*)d_in[0];
    const int* ei    = (const int*)d_in[1];
    const int* batch = (const int*)d_in[2];
    const float* W[5]  = {nullptr, (const float*)d_in[3],  (const float*)d_in[7],
                                   (const float*)d_in[11], (const float*)d_in[15]};
    const float* bb[5] = {nullptr, (const float*)d_in[4],  (const float*)d_in[8],
                                   (const float*)d_in[12], (const float*)d_in[16]};
    const float* gg[5] = {nullptr, (const float*)d_in[5],  (const float*)d_in[9],
                                   (const float*)d_in[13], (const float*)d_in[17]};
    const float* bt[5] = {nullptr, (const float*)d_in[6],  (const float*)d_in[10],
                                   (const float*)d_in[14], (const float*)d_in[18]};
    const float* fw1 = (const float*)d_in[19];
    const float* fb1 = (const float*)d_in[20];
    const float* fw2 = (const float*)d_in[21];
    const float* fb2 = (const float*)d_in[22];
    float* out = (float*)d_out;

    const int* row = ei;
    const int* col = ei + NE;

    float* ws = (float*)d_ws;
    int*   cursor  = (int*)ws;              // N
    int*   eidx    = (int*)(ws + 50000);    // E
    float* dinv    = ws + 850000;           // N
    float* xd      = ws + 900000;           // N
    int*   bsum    = (int*)(ws + 950000);   // NBIN
    float* s       = ws + 951000;           // N
    float* stats   = ws + 1001008;          // 2
    float* bnsum   = ws + 1001072;          // 64
    float* bnsq    = ws + 1001136;          // 64
    float* pooled  = ws + 1001360;          // 64*64
    float* cnt     = ws + 1005456;          // 64
    int*   gcnt    = (int*)(ws + 1056000);  // NBIN
    __half* hbuf   = (__half*)(ws + 1100000); // N*64 halves (bins alias pre-layer2)
    int*   bins    = (int*)(ws + 1100000);  // NBIN*BINCAP ints
    float* aggbuf  = ws + 4300000;          // N*64

    const int B = 256;

    // CSR build (binned) + dinv + xd
    hipMemsetAsync(gcnt, 0, NBIN * sizeof(int), stream);
    k_binscatter<<<SCH_NBLK, B, 0, stream>>>(row, col, gcnt, bins);
    k_binscan<<<NBIN, B, 0, stream>>>(gcnt, bins, x, cursor, bsum, dinv, xd);
    k_scan_top<<<1, SCAN_B, 0, stream>>>(bsum, stats);
    // fill eidx + layer-1 scalar propagation + stats
    k_binfill_l1<<<NBIN, B, 0, stream>>>(gcnt, bins, cursor, bsum, eidx, xd, x, dinv, s, stats);

    // layer 2
    k_mm_l1<<<MM_NBLK, B, 0, stream>>>(s, stats, W[1], gg[1], bt[1], W[2], dinv, hbuf);
    k_gather<<<MM_NBLK, B, 0, stream>>>(cursor, bsum, eidx, dinv, hbuf, bb[2], aggbuf, bnsum, bnsq);
    k_bn_stats<<<512, B, 0, stream>>>(aggbuf, bnsum, bnsq, nullptr, nullptr);

    // layers 3,4
    for (int L = 3; L <= 4; ++L) {
        k_mm_bn<<<MM_NBLK, B, 0, stream>>>(aggbuf, bnsum, bnsq, gg[L - 1], bt[L - 1], W[L], dinv, hbuf);
        k_gather<<<MM_NBLK, B, 0, stream>>>(cursor, bsum, eidx, dinv, hbuf, bb[L], aggbuf, bnsum, bnsq);
        k_bn_stats<<<512, B, 0, stream>>>(aggbuf, bnsum, bnsq,
                                          (L == 4) ? pooled : nullptr, (L == 4) ? cnt : nullptr);
    }

    // fused finalize+BN+pool (segmented) + FC
    k_pool_bn<<<512, B, 0, stream>>>(aggbuf, bnsum, bnsq, gg[4], bt[4], batch, pooled, cnt);
    k_fc<<<NG, 128, 0, stream>>>(pooled, cnt, fw1, fb1, fw2, fb2, out);
}

// Round 12
// 297.695 us; speedup vs baseline: 1.7213x; 1.0286x over previous
//
#include <hip/hip_runtime.h>
#include <hip/hip_fp16.h>

#define NN 50000
#define NE 800000
#define NG 64
#define FD 64
#define BN_EPS 1e-5f
#define SCAN_B 256
#define NBIN 98            // ceil(50000/512)
#define BINCAP 12288
#define SCH 4096
#define SCH_NBLK ((NE + SCH - 1) / SCH)          // 196
#define INV_NN (1.0f / NN)
#define MM_NODES 16
#define MMB_NBLK ((NN + MM_NODES - 1) / MM_NODES)  // 3125
#define G_NBLK ((NN + 3) / 4)                      // 12500

// ---------------- CSR build: binned two-pass ----------------
__global__ __launch_bounds__(256) void k_binscatter(const int* __restrict__ row,
                                                    const int* __restrict__ col,
                                                    int* __restrict__ gcnt,
                                                    int* __restrict__ bins) {
    __shared__ int stage[SCH];
    __shared__ unsigned char stageb[SCH];
    __shared__ int cnt[NBIN], off[NBIN], cur[NBIN], gbase[NBIN];
    int t = threadIdx.x;
    int e0 = blockIdx.x * SCH;
    int nk = NE - e0; if (nk > SCH) nk = SCH;
    if (nk <= 0) return;
    for (int b = t; b < NBIN; b += 256) cnt[b] = 0;
    __syncthreads();
    for (int k = t; k < nk; k += 256) {
        int c = col[e0 + k];
        atomicAdd(&cnt[c >> 9], 1);
    }
    __syncthreads();
    if (t == 0) {
        int run = 0;
        for (int b = 0; b < NBIN; ++b) { off[b] = run; run += cnt[b]; }
    }
    __syncthreads();
    if (t < NBIN) {
        cur[t] = off[t];
        gbase[t] = t * BINCAP + atomicAdd(&gcnt[t], cnt[t]);
    }
    __syncthreads();
    for (int k = t; k < nk; k += 256) {
        int c = col[e0 + k];
        int r = row[e0 + k];
        int b = c >> 9;
        int pos = atomicAdd(&cur[b], 1);
        stage[pos] = ((c & 511) << 16) | r;
        stageb[pos] = (unsigned char)b;
    }
    __syncthreads();
    for (int k = t; k < nk; k += 256) {
        int b = stageb[k];
        bins[gbase[b] + (k - off[b])] = stage[k];
    }
}

// per-bin degree hist + in-block scan + dinv + xd
__global__ __launch_bounds__(256) void k_binscan(const int* __restrict__ gcnt,
                                                 const int* __restrict__ bins,
                                                 const float* __restrict__ x,
                                                 int* __restrict__ cursor,
                                                 int* __restrict__ bsum,
                                                 float* __restrict__ dinv,
                                                 float* __restrict__ xd) {
    __shared__ int ldeg[512];
    __shared__ int psc[256];
    int b = blockIdx.x, t = threadIdx.x;
    for (int l = t; l < 512; l += 256) ldeg[l] = 0;
    __syncthreads();
    int nb = gcnt[b];
    const int* bp = bins + b * BINCAP;
    for (int k = t; k < nb; k += 256) atomicAdd(&ldeg[bp[k] >> 16], 1);
    __syncthreads();
    int d0 = ldeg[2 * t], d1 = ldeg[2 * t + 1];
    int pv = d0 + d1;
    psc[t] = pv;
    __syncthreads();
    for (int off = 1; off < 256; off <<= 1) {
        int u = (t >= off) ? psc[t - off] : 0;
        __syncthreads();
        psc[t] += u;
        __syncthreads();
    }
    int excl = psc[t] - pv;
    int base = b << 9;
    int i0 = base + 2 * t, i1 = i0 + 1;
    if (i0 < NN) {
        cursor[i0] = excl;
        float dv = rsqrtf((float)d0 + 1.0f);
        dinv[i0] = dv; xd[i0] = x[i0] * dv;
    }
    if (i1 < NN) {
        cursor[i1] = excl + d0;
        float dv = rsqrtf((float)d1 + 1.0f);
        dinv[i1] = dv; xd[i1] = x[i1] * dv;
    }
    if (t == 255) bsum[b] = psc[255];
}

// scan the 98 bin sums -> exclusive bin offsets; zero stats
__global__ __launch_bounds__(SCAN_B) void k_scan_top(int* __restrict__ bsum,
                                                     float* __restrict__ stats) {
    __shared__ int sh[SCAN_B];
    int t = threadIdx.x;
    if (t < 2) stats[t] = 0.0f;
    int v = (t < NBIN) ? bsum[t] : 0;
    sh[t] = v;
    __syncthreads();
    for (int off = 1; off < SCAN_B; off <<= 1) {
        int u = (t >= off) ? sh[t - off] : 0;
        __syncthreads();
        sh[t] += u;
        __syncthreads();
    }
    if (t < NBIN) bsum[t] = sh[t] - v;
}

// per-bin fill of eidx (u16) + fused layer-1 scalar propagation + stats
__global__ __launch_bounds__(256) void k_binfill_l1(const int* __restrict__ gcnt,
                                                    const int* __restrict__ bins,
                                                    const int* __restrict__ cursor,
                                                    const int* __restrict__ bsum,
                                                    unsigned short* __restrict__ eidx,
                                                    const float* __restrict__ xd,
                                                    const float* __restrict__ x,
                                                    const float* __restrict__ dinv,
                                                    float* __restrict__ s,
                                                    float* __restrict__ stats) {
    __shared__ int lstart[512], lcur[512];
    __shared__ float ls[256], lq[256];
    int b = blockIdx.x, t = threadIdx.x;
    int base = b << 9;
    int bofs = bsum[b];
    for (int l = t; l < 512; l += 256) {
        int i = base + l;
        int st = (i < NN) ? cursor[i] + bofs : 0;
        lstart[l] = st; lcur[l] = st;
    }
    __syncthreads();
    int nb = gcnt[b];
    const int* bp = bins + b * BINCAP;
    for (int k = t; k < nb; k += 256) {
        int v = bp[k];
        int pos = atomicAdd(&lcur[v >> 16], 1);
        eidx[pos] = (unsigned short)(v & 0xFFFF);
    }
    __syncthreads();
    float a = 0.0f, q = 0.0f;
    #pragma unroll
    for (int half = 0; half < 2; ++half) {
        int l = t + half * 256;
        int i = base + l;
        if (i < NN) {
            float acc = 0.0f;
            int e0 = lstart[l], e1 = lcur[l];
            for (int k = e0; k < e1; ++k) acc += xd[eidx[k]];
            float di = dinv[i];
            float sv = di * (acc + di * x[i]);
            s[i] = sv;
            a += sv; q += sv * sv;
        }
    }
    ls[t] = a; lq[t] = q;
    __syncthreads();
    for (int st = 128; st > 0; st >>= 1) {
        if (t < st) { ls[t] += ls[t + st]; lq[t] += lq[t + st]; }
        __syncthreads();
    }
    if (t == 0) { atomicAdd(&stats[0], ls[0]); atomicAdd(&stats[1], lq[0]); }
}

// ---------------- fused coeffs + activation + 64x64 matmul (16 nodes/block, fp16 h'=h*dinv) ----------------
__global__ __launch_bounds__(256) void k_mm_l1(const float* __restrict__ s,
                                               const float* __restrict__ stats,
                                               const float* __restrict__ W1,
                                               const float* __restrict__ g1,
                                               const float* __restrict__ bt1,
                                               const float* __restrict__ W,
                                               const float* __restrict__ dinv,
                                               __half* __restrict__ h) {
    __shared__ float Ws[64 * 64];
    __shared__ float xs[4 * 64];
    __shared__ float als[64], cls[64];
    int t = threadIdx.x;
    for (int k = t; k < 64 * 64; k += 256) Ws[k] = W[k];
    if (t < 64) {
        float mean = stats[0] * INV_NN;
        float var  = stats[1] * INV_NN - mean * mean;
        float w = W1[t];
        float rinv = rsqrtf(var * w * w + BN_EPS);
        float a = g1[t] * w * rinv;
        als[t] = a;
        cls[t] = bt1[t] - a * mean;
    }
    int j = t & 63, n = t >> 6;
    #pragma unroll
    for (int it = 0; it < MM_NODES / 4; ++it) {
        int node = blockIdx.x * MM_NODES + it * 4 + n;
        float sv = (node < NN) ? s[node] : 0.0f;
        __syncthreads();
        xs[t] = fmaxf(als[j] * sv + cls[j], 0.0f);
        __syncthreads();
        if (node < NN) {
            float acc = 0.f;
            #pragma unroll
            for (int k = 0; k < 64; ++k) acc += xs[n * 64 + k] * Ws[k * 64 + j];
            h[node * 64 + j] = __float2half(acc * dinv[node]);
        }
    }
}

__global__ __launch_bounds__(256) void k_mm_bn(const float* __restrict__ src,
                                               const float* __restrict__ bnsum,
                                               const float* __restrict__ bnsq,
                                               const float* __restrict__ g,
                                               const float* __restrict__ bt,
                                               const float* __restrict__ W,
                                               const float* __restrict__ dinv,
                                               __half* __restrict__ h) {
    __shared__ float Ws[64 * 64];
    __shared__ float xs[4 * 64];
    __shared__ float scl[64], shf[64];
    int t = threadIdx.x;
    for (int k = t; k < 64 * 64; k += 256) Ws[k] = W[k];
    if (t < 64) {
        float mean = bnsum[t] * INV_NN;
        float var  = bnsq[t] * INV_NN - mean * mean;
        float rinv = rsqrtf(var + BN_EPS);
        float sc = g[t] * rinv;
        scl[t] = sc;
        shf[t] = bt[t] - sc * mean;
    }
    int j = t & 63, n = t >> 6;
    #pragma unroll
    for (int it = 0; it < MM_NODES / 4; ++it) {
        int node = blockIdx.x * MM_NODES + it * 4 + n;
        float v = (node < NN) ? src[node * 64 + j] : 0.0f;
        __syncthreads();
        xs[t] = fmaxf(scl[j] * v + shf[j], 0.0f);
        __syncthreads();
        if (node < NN) {
            float acc = 0.f;
            #pragma unroll
            for (int k = 0; k < 64; ++k) acc += xs[n * 64 + k] * Ws[k * 64 + j];
            h[node * 64 + j] = __float2half(acc * dinv[node]);
        }
    }
}

// ---------------- CSR gather aggregation ----------------
// h is pre-scaled by dinv[src]; agg[c] = dinv[c]*(sum_r h'[r] + h'[c]) + b
__global__ __launch_bounds__(256) void k_gather(const int* __restrict__ cursor,
                                                const int* __restrict__ bsum,
                                                const unsigned short* __restrict__ eidx,
                                                const float* __restrict__ dinv,
                                                const __half* __restrict__ h,
                                                const float* __restrict__ b,
                                                float* __restrict__ agg,
                                                float* __restrict__ bnsumz,
                                                float* __restrict__ bnsqz) {
    if (blockIdx.x == 0) {
        int tt = threadIdx.x;
        if (tt < 64) bnsumz[tt] = 0.0f;
        else if (tt < 128) bnsqz[tt - 64] = 0.0f;
    }
    int node = blockIdx.x * 4 + (threadIdx.x >> 6);
    if (node >= NN) return;
    int lane = threadIdx.x & 63;
    int eslot = lane >> 3;          // 0..7
    int fb = (lane & 7) << 3;       // feature base in halves
    int start = cursor[node] + bsum[node >> 9];
    int end = (node < NN - 1) ? cursor[node + 1] + bsum[(node + 1) >> 9] : NE;
    float a0 = 0.f, a1 = 0.f, a2 = 0.f, a3 = 0.f, a4 = 0.f, a5 = 0.f, a6 = 0.f, a7 = 0.f;
    float c0 = 0.f, c1 = 0.f, c2 = 0.f, c3 = 0.f, c4 = 0.f, c5 = 0.f, c6 = 0.f, c7 = 0.f;
    int e = start + eslot;
    for (; e + 8 < end; e += 16) {
        int r0 = eidx[e], r1 = eidx[e + 8];
        uint4 u = *reinterpret_cast<const uint4*>(&h[(r0 << 6) + fb]);
        uint4 v = *reinterpret_cast<const uint4*>(&h[(r1 << 6) + fb]);
        float2 p;
        p = __half22float2(*reinterpret_cast<__half2*>(&u.x)); a0 += p.x; a1 += p.y;
        p = __half22float2(*reinterpret_cast<__half2*>(&u.y)); a2 += p.x; a3 += p.y;
        p = __half22float2(*reinterpret_cast<__half2*>(&u.z)); a4 += p.x; a5 += p.y;
        p = __half22float2(*reinterpret_cast<__half2*>(&u.w)); a6 += p.x; a7 += p.y;
        p = __half22float2(*reinterpret_cast<__half2*>(&v.x)); c0 += p.x; c1 += p.y;
        p = __half22float2(*reinterpret_cast<__half2*>(&v.y)); c2 += p.x; c3 += p.y;
        p = __half22float2(*reinterpret_cast<__half2*>(&v.z)); c4 += p.x; c5 += p.y;
        p = __half22float2(*reinterpret_cast<__half2*>(&v.w)); c6 += p.x; c7 += p.y;
    }
    if (e < end) {
        int r = eidx[e];
        uint4 u = *reinterpret_cast<const uint4*>(&h[(r << 6) + fb]);
        float2 p;
        p = __half22float2(*reinterpret_cast<__half2*>(&u.x)); a0 += p.x; a1 += p.y;
        p = __half22float2(*reinterpret_cast<__half2*>(&u.y)); a2 += p.x; a3 += p.y;
        p = __half22float2(*reinterpret_cast<__half2*>(&u.z)); a4 += p.x; a5 += p.y;
        p = __half22float2(*reinterpret_cast<__half2*>(&u.w)); a6 += p.x; a7 += p.y;
    }
    a0 += c0; a1 += c1; a2 += c2; a3 += c3; a4 += c4; a5 += c5; a6 += c6; a7 += c7;
    #pragma unroll
    for (int d = 8; d <= 32; d <<= 1) {
        a0 += __shfl_xor(a0, d); a1 += __shfl_xor(a1, d);
        a2 += __shfl_xor(a2, d); a3 += __shfl_xor(a3, d);
        a4 += __shfl_xor(a4, d); a5 += __shfl_xor(a5, d);
        a6 += __shfl_xor(a6, d); a7 += __shfl_xor(a7, d);
    }
    if (eslot == 0) {
        float dc = dinv[node];
        uint4 u = *reinterpret_cast<const uint4*>(&h[(node << 6) + fb]);
        float2 p;
        p = __half22float2(*reinterpret_cast<__half2*>(&u.x)); a0 += p.x; a1 += p.y;
        p = __half22float2(*reinterpret_cast<__half2*>(&u.y)); a2 += p.x; a3 += p.y;
        p = __half22float2(*reinterpret_cast<__half2*>(&u.z)); a4 += p.x; a5 += p.y;
        p = __half22float2(*reinterpret_cast<__half2*>(&u.w)); a6 += p.x; a7 += p.y;
        const float4 bv0 = *reinterpret_cast<const float4*>(&b[fb]);
        const float4 bv1 = *reinterpret_cast<const float4*>(&b[fb + 4]);
        float4 o0, o1;
        o0.x = dc * a0 + bv0.x; o0.y = dc * a1 + bv0.y;
        o0.z = dc * a2 + bv0.z; o0.w = dc * a3 + bv0.w;
        o1.x = dc * a4 + bv1.x; o1.y = dc * a5 + bv1.y;
        o1.z = dc * a6 + bv1.z; o1.w = dc * a7 + bv1.w;
        *reinterpret_cast<float4*>(&agg[node * 64 + fb]) = o0;
        *reinterpret_cast<float4*>(&agg[node * 64 + fb + 4]) = o1;
    }
}

// ---------------- batchnorm stats (optionally zeros pooled/cnt) ----------------
__global__ __launch_bounds__(256) void k_bn_stats(const float* __restrict__ agg,
                                                  float* __restrict__ bnsum, float* __restrict__ bnsq,
                                                  float* __restrict__ pooledz, float* __restrict__ cntz) {
    if (pooledz != nullptr && blockIdx.x == 0) {
        for (int k = threadIdx.x; k < 64 * 64; k += 256) pooledz[k] = 0.0f;
        if (threadIdx.x < 64) cntz[threadIdx.x] = 0.0f;
    }
    __shared__ float ls[256], lq[256];
    int j = threadIdx.x & 63, nl = threadIdx.x >> 6;
    float a = 0.f, b = 0.f;
    for (int i = blockIdx.x * 4 + nl; i < NN; i += gridDim.x * 4) {
        float v = agg[i * 64 + j]; a += v; b += v * v;
    }
    ls[threadIdx.x] = a; lq[threadIdx.x] = b; __syncthreads();
    if (threadIdx.x < 128) { ls[threadIdx.x] += ls[threadIdx.x + 128]; lq[threadIdx.x] += lq[threadIdx.x + 128]; }
    __syncthreads();
    if (threadIdx.x < 64) {
        atomicAdd(&bnsum[j], ls[threadIdx.x] + ls[threadIdx.x + 64]);
        atomicAdd(&bnsq[j],  lq[threadIdx.x] + lq[threadIdx.x + 64]);
    }
}

// ---------------- fused BN-finalize + BN + pooling (segmented) ----------------
__global__ __launch_bounds__(256) void k_pool_bn(const float* __restrict__ agg,
                                                 const float* __restrict__ bnsum,
                                                 const float* __restrict__ bnsq,
                                                 const float* __restrict__ g4,
                                                 const float* __restrict__ bt4,
                                                 const int* __restrict__ batch,
                                                 float* __restrict__ pooled,
                                                 float* __restrict__ cnt) {
    const int wpb = 4;
    int wave = blockIdx.x * wpb + (threadIdx.x >> 6);
    int lane = threadIdx.x & 63;
    const int nwaves = gridDim.x * wpb;
    int chunk = (NN + nwaves - 1) / nwaves;
    int i0 = wave * chunk;
    int i1 = i0 + chunk; if (i1 > NN) i1 = NN;
    if (i0 >= NN) return;
    float mean = bnsum[lane] * INV_NN;
    float var  = bnsq[lane] * INV_NN - mean * mean;
    float rinv = rsqrtf(var + BN_EPS);
    float sc = g4[lane] * rinv;
    float sh = bt4[lane] - sc * mean;
    float acc = 0.0f;
    int curb = batch[i0];
    int runlen = 0;
    for (int i = i0; i < i1; ++i) {
        int b = batch[i];
        if (b != curb) {
            atomicAdd(&pooled[curb * 64 + lane], acc);
            if (lane == 0) atomicAdd(&cnt[curb], (float)runlen);
            acc = 0.0f; runlen = 0; curb = b;
        }
        acc += fmaxf(sc * agg[i * 64 + lane] + sh, 0.0f);
        ++runlen;
    }
    atomicAdd(&pooled[curb * 64 + lane], acc);
    if (lane == 0) atomicAdd(&cnt[curb], (float)runlen);
}

__global__ __launch_bounds__(128) void k_fc(const float* __restrict__ pooled, const float* __restrict__ cnt,
                                            const float* __restrict__ fw1, const float* __restrict__ fb1,
                                            const float* __restrict__ fw2, const float* __restrict__ fb2,
                                            float* __restrict__ out) {
    __shared__ float p[64], hsh[128];
    int g = blockIdx.x, t = threadIdx.x;
    if (t < 64) {
        float c = cnt[g]; c = c < 1.f ? 1.f : c;
        p[t] = pooled[g * 64 + t] / c;
    }
    __syncthreads();
    float acc = fb1[t];
    #pragma unroll 8
    for (int k = 0; k < 64; ++k) acc += p[k] * fw1[t * 64 + k];
    hsh[t] = fmaxf(acc, 0.f);
    __syncthreads();
    if (t < 10) {
        float o = fb2[t];
        #pragma unroll 8
        for (int k = 0; k < 128; ++k) o += hsh[k] * fw2[t * 128 + k];
        out[g * 10 + t] = o;
    }
}

// ---------------- launch ----------------
extern "C" void kernel_launch(void* const* d_in, const int* in_sizes, int n_in,
                              void* d_out, int out_size, void* d_ws, size_t ws_size,
                              hipStream_t stream) {
    const float* x   = (const float*)d_in[0];
    const int* ei    = (const int*)d_in[1];
    const int* batch = (const int*)d_in[2];
    const float* W[5]  = {nullptr, (const float*)d_in[3],  (const float*)d_in[7],
                                   (const float*)d_in[11], (const float*)d_in[15]};
    const float* bb[5] = {nullptr, (const float*)d_in[4],  (const float*)d_in[8],
                                   (const float*)d_in[12], (const float*)d_in[16]};
    const float* gg[5] = {nullptr, (const float*)d_in[5],  (const float*)d_in[9],
                                   (const float*)d_in[13], (const float*)d_in[17]};
    const float* bt[5] = {nullptr, (const float*)d_in[6],  (const float*)d_in[10],
                                   (const float*)d_in[14], (const float*)d_in[18]};
    const float* fw1 = (const float*)d_in[19];
    const float* fb1 = (const float*)d_in[20];
    const float* fw2 = (const float*)d_in[21];
    const float* fb2 = (const float*)d_in[22];
    float* out = (float*)d_out;

    const int* row = ei;
    const int* col = ei + NE;

    float* ws = (float*)d_ws;
    int*   cursor  = (int*)ws;                    // N
    unsigned short* eidx = (unsigned short*)(ws + 50000);  // E u16 = 400000 float slots
    float* dinv    = ws + 850000;                 // N
    float* xd      = ws + 900000;                 // N
    int*   bsum    = (int*)(ws + 950000);         // NBIN
    float* s       = ws + 951000;                 // N
    float* stats   = ws + 1001008;                // 2
    float* bnsum   = ws + 1001072;                // 64
    float* bnsq    = ws + 1001136;                // 64
    float* pooled  = ws + 1001360;                // 64*64
    float* cnt     = ws + 1005456;                // 64
    int*   gcnt    = (int*)(ws + 1056000);        // NBIN
    __half* hbuf   = (__half*)(ws + 1100000);     // N*64 halves (bins alias pre-layer2)
    int*   bins    = (int*)(ws + 1100000);        // NBIN*BINCAP ints
    float* aggbuf  = ws + 4300000;                // N*64

    const int B = 256;

    // CSR build (binned) + dinv + xd
    hipMemsetAsync(gcnt, 0, NBIN * sizeof(int), stream);
    k_binscatter<<<SCH_NBLK, B, 0, stream>>>(row, col, gcnt, bins);
    k_binscan<<<NBIN, B, 0, stream>>>(gcnt, bins, x, cursor, bsum, dinv, xd);
    k_scan_top<<<1, SCAN_B, 0, stream>>>(bsum, stats);
    // fill eidx (u16) + layer-1 scalar propagation + stats
    k_binfill_l1<<<NBIN, B, 0, stream>>>(gcnt, bins, cursor, bsum, eidx, xd, x, dinv, s, stats);

    // layer 2
    k_mm_l1<<<MMB_NBLK, B, 0, stream>>>(s, stats, W[1], gg[1], bt[1], W[2], dinv, hbuf);
    k_gather<<<G_NBLK, B, 0, stream>>>(cursor, bsum, eidx, dinv, hbuf, bb[2], aggbuf, bnsum, bnsq);
    k_bn_stats<<<512, B, 0, stream>>>(aggbuf, bnsum, bnsq, nullptr, nullptr);

    // layers 3,4
    for (int L = 3; L <= 4; ++L) {
        k_mm_bn<<<MMB_NBLK, B, 0, stream>>>(aggbuf, bnsum, bnsq, gg[L - 1], bt[L - 1], W[L], dinv, hbuf);
        k_gather<<<G_NBLK, B, 0, stream>>>(cursor, bsum, eidx, dinv, hbuf, bb[L], aggbuf, bnsum, bnsq);
        k_bn_stats<<<512, B, 0, stream>>>(aggbuf, bnsum, bnsq,
                                          (L == 4) ? pooled : nullptr, (L == 4) ? cnt : nullptr);
    }

    // fused finalize+BN+pool (segmented) + FC
    k_pool_bn<<<512, B, 0, stream>>>(aggbuf, bnsum, bnsq, gg[4], bt[4], batch, pooled, cnt);
    k_fc<<<NG, 128, 0, stream>>>(pooled, cnt, fw1, fb1, fw2, fb2, out);
}